// Round 2
// baseline (5066.273 us; speedup 1.0000x reference)
//
#include <hip/hip_runtime.h>
#include <math.h>

// ---------------- types ----------------
typedef __attribute__((ext_vector_type(8))) short bf16x8;
typedef __attribute__((ext_vector_type(4))) short short4v;
typedef __attribute__((ext_vector_type(4))) float f32x4;

__device__ __forceinline__ float sigm(float x) { return 1.f / (1.f + expf(-x)); }

__device__ __forceinline__ float bf2f(short x) {
    unsigned u = ((unsigned)(unsigned short)x) << 16;
    float f; __builtin_memcpy(&f, &u, 4); return f;
}
__device__ __forceinline__ short f2bf(float f) {
    unsigned u; __builtin_memcpy(&u, &f, 4);
    unsigned r = (u + 0x7fffu + ((u >> 16) & 1u)) >> 16;
    return (short)r;
}

// ---------------- hand-rolled grid barrier (graph-capture-safe) --------------
// Generation-based: re-entrant, safe under rocprof dispatch replay (only
// requires cnt==0 at kernel entry, which the protocol restores).
__device__ __forceinline__ void grid_barrier(unsigned* cnt, unsigned* gen,
                                             unsigned nblk) {
    __threadfence();                 // release: drain this block's writes (wbL2)
    __syncthreads();                 // all stores at vmcnt(0) before arrival
    if (threadIdx.x == 0) {
        unsigned g = __hip_atomic_load(gen, __ATOMIC_RELAXED,
                                       __HIP_MEMORY_SCOPE_AGENT);
        if (__hip_atomic_fetch_add(cnt, 1u, __ATOMIC_ACQ_REL,
                                   __HIP_MEMORY_SCOPE_AGENT) == nblk - 1u) {
            // last arrival: reset cnt BEFORE releasing gen
            __hip_atomic_store(cnt, 0u, __ATOMIC_RELAXED,
                               __HIP_MEMORY_SCOPE_AGENT);
            __hip_atomic_store(gen, g + 1u, __ATOMIC_RELEASE,
                               __HIP_MEMORY_SCOPE_AGENT);
        } else {
            while (__hip_atomic_load(gen, __ATOMIC_ACQUIRE,
                                     __HIP_MEMORY_SCOPE_AGENT) == g) {
                __builtin_amdgcn_s_sleep(1);
            }
        }
    }
    __syncthreads();
    __threadfence();                 // acquire: invalidate stale L1/L2 lines
}

// ---------------- workspace layout (byte offsets) ----------------
#define OFF_C1      0u           // barrier counters (256 B used), zeroed in-graph
#define OFF_C2      262144u
#define OFF_H2A     524288u      // 64x1024 bf16  131072
#define OFF_H2B     655360u      // 64x1024 bf16  131072
#define OFF_H1HI    786432u      // 33 x 64x1024 bf16  4325376
#define OFF_H1LO    5111808u     // 33 x 64x1024 bf16  4325376
#define OFF_H1F     9437184u     // 32 x 64x1024 f32   8388608
#define OFF_X0HI    17825792u    // 2048x1024 bf16 4194304  (aliased by VHI later)
#define OFF_X0LO    22020096u    // 2048x1024 bf16 4194304  (aliased by VLO later)
#define OFF_B1      26214400u    // 4096 f32 16384
#define OFF_B2      26230784u    // 4096 f32 16384
#define OFF_WHH1HI  26247168u    // 4096x1024 bf16 8388608
#define OFF_WHH1LO  34635776u
#define OFF_WIH1HI  43024384u
#define OFF_WIH1LO  51412992u
#define OFF_WHH2HI  59801600u
#define OFF_WVHI    68190208u
#define OFF_WVLO    76578816u
#define OFF_WH2HI   84967424u
#define OFF_X12     93356032u    // 2048x4096 f32 33554432 (also lo-dump during prep)

// ---------------- prep kernels ----------------
__global__ __launch_bounds__(256) void zero_ws(float4* __restrict__ p) {
    int i = blockIdx.x * 256 + threadIdx.x;
    p[i] = make_float4(0.f, 0.f, 0.f, 0.f);
}

__global__ __launch_bounds__(256) void perm_w_split(const float* __restrict__ src,
                                                    short* __restrict__ hi,
                                                    short* __restrict__ lo,
                                                    int rs, int co) {
    int idx = blockIdx.x * 256 + threadIdx.x;   // 4096 blocks
    int jp = idx >> 8;
    int kq = idx & 255;
    int jsrc = (jp & 3) * 1024 + (jp >> 2);
    float4 v = *(const float4*)(src + (size_t)jsrc * rs + co + kq * 4);
    float a[4] = {v.x, v.y, v.z, v.w};
    short4v h, l;
    #pragma unroll
    for (int e = 0; e < 4; e++) {
        short q = f2bf(a[e]);
        h[e] = q;
        l[e] = f2bf(a[e] - bf2f(q));
    }
    *(short4v*)(hi + (size_t)jp * 1024 + kq * 4) = h;
    *(short4v*)(lo + (size_t)jp * 1024 + kq * 4) = l;
}

__global__ __launch_bounds__(256) void bias_prep(
    const float* __restrict__ bi1, const float* __restrict__ bh1,
    const float* __restrict__ bi2, const float* __restrict__ bh2,
    float* __restrict__ b1p, float* __restrict__ b2p) {
    int jp = blockIdx.x * 256 + threadIdx.x;     // 16 blocks
    int j = (jp & 3) * 1024 + (jp >> 2);
    b1p[jp] = bi1[j] + bh1[j];
    b2p[jp] = bi2[j] + bh2[j];
}

__global__ __launch_bounds__(256) void gather_x0_split(
    const int* __restrict__ tokens, const float* __restrict__ emb,
    short* __restrict__ hi, short* __restrict__ lo) {
    int idx = blockIdx.x * 256 + threadIdx.x;    // 2048 blocks
    int p = idx >> 8;
    int k0 = (idx & 255) * 4;
    int tok = tokens[p];
    float4 v = *(const float4*)(emb + (size_t)tok * 1024 + k0);
    float a[4] = {v.x, v.y, v.z, v.w};
    short4v h, l;
    #pragma unroll
    for (int e = 0; e < 4; e++) {
        short q = f2bf(a[e]);
        h[e] = q;
        l[e] = f2bf(a[e] - bf2f(q));
    }
    *(short4v*)(hi + (size_t)p * 1024 + k0) = h;
    *(short4v*)(lo + (size_t)p * 1024 + k0) = l;
}

// ---------------- big GEMM (unchanged) ----------------
__global__ __launch_bounds__(256) void big_gemm(
    const short* __restrict__ A0, const short* __restrict__ A1s,
    const short* __restrict__ A2s, const short* __restrict__ A3s,
    const short* __restrict__ B0, const short* __restrict__ B1s,
    const short* __restrict__ B2s, const short* __restrict__ B3s,
    const float* __restrict__ bias, float* __restrict__ C, int K) {
    __shared__ short As[128 * 40];
    __shared__ short Bs[128 * 40];
    int tid = threadIdx.x;
    int n0 = blockIdx.x * 128;
    int m0 = blockIdx.y * 128;
    int lane = tid & 63, w = tid >> 6;
    int wm = (w >> 1) * 64, wn = (w & 1) * 64;
    int quad = lane >> 4, l16 = lane & 15;
    int srow = tid >> 2;
    int skc = (tid & 3) * 8;

    f32x4 acc[4][4];
    f32x4 z4 = {0.f, 0.f, 0.f, 0.f};
    #pragma unroll
    for (int i = 0; i < 4; i++)
        #pragma unroll
        for (int j = 0; j < 4; j++) acc[i][j] = z4;

    for (int k0 = 0; k0 < K; k0 += 32) {
        int seg = k0 >> 10;
        const short* Ab = (seg == 0) ? A0 : (seg == 1) ? A1s : (seg == 2) ? A2s : A3s;
        const short* Bb = (seg == 0) ? B0 : (seg == 1) ? B1s : (seg == 2) ? B2s : B3s;
        int kk = (k0 & 1023) + skc;
        const short* ga = Ab + (size_t)(m0 + srow) * 1024 + kk;
        const short* gb = Bb + (size_t)(n0 + srow) * 1024 + kk;
        bf16x8 av0 = *(const bf16x8*)ga;
        bf16x8 av1 = *(const bf16x8*)(ga + 64 * 1024);
        bf16x8 bv0 = *(const bf16x8*)gb;
        bf16x8 bv1 = *(const bf16x8*)(gb + 64 * 1024);
        __syncthreads();
        *(bf16x8*)&As[srow * 40 + skc] = av0;
        *(bf16x8*)&As[(srow + 64) * 40 + skc] = av1;
        *(bf16x8*)&Bs[srow * 40 + skc] = bv0;
        *(bf16x8*)&Bs[(srow + 64) * 40 + skc] = bv1;
        __syncthreads();
        bf16x8 af[4], bfr[4];
        #pragma unroll
        for (int im = 0; im < 4; im++)
            af[im] = *(const bf16x8*)&As[(wm + im * 16 + l16) * 40 + quad * 8];
        #pragma unroll
        for (int in = 0; in < 4; in++)
            bfr[in] = *(const bf16x8*)&Bs[(wn + in * 16 + l16) * 40 + quad * 8];
        #pragma unroll
        for (int im = 0; im < 4; im++)
            #pragma unroll
            for (int in = 0; in < 4; in++)
                acc[im][in] = __builtin_amdgcn_mfma_f32_16x16x32_bf16(
                    af[im], bfr[in], acc[im][in], 0, 0, 0);
    }
    #pragma unroll
    for (int in = 0; in < 4; in++) {
        int j = n0 + wn + in * 16 + l16;
        float bsv = bias[j];
        #pragma unroll
        for (int im = 0; im < 4; im++) {
            #pragma unroll
            for (int r = 0; r < 4; r++) {
                int p = m0 + wm + im * 16 + quad * 4 + r;
                C[(size_t)p * 4096 + j] = acc[im][in][r] + bsv;
            }
        }
    }
}

// ---------------- fused layer-1 recurrence (persistent, own barrier) ---------
// 256 blocks x 256 thr, 1+/CU. Block g owns gate-rows [g*16,g*16+16) of whh1.
// W-hi pinned in LDS (padded stride 1032 -> conflict-free); W-lo from global
// (L2-resident). Cell state register-resident. LDS 49.4 KB -> 3 blocks/CU can
// co-reside, so the 256-block grid is always fully resident (no deadlock).
__global__ __launch_bounds__(256, 1) void lstm1_fused(
    const short* __restrict__ Whi, const short* __restrict__ Wlo,
    const float* __restrict__ X12,
    short* __restrict__ H1hi, short* __restrict__ H1lo,
    float* __restrict__ H1f,
    unsigned* __restrict__ bcnt, unsigned* __restrict__ bgen) {
    __shared__ short wsh[16 * 1032];
    __shared__ float red[4 * 64 * 16];

    int tid = threadIdx.x;
    int lane = tid & 63, w = tid >> 6;
    int quad = lane >> 4, l16 = lane & 15;
    int g = blockIdx.x;
    int kbase = w * 256;

    // stage hi-weight slice into LDS once
    for (int i = tid; i < 2048; i += 256) {
        int r = i >> 7;
        int k = (i & 127) * 8;
        *(bf16x8*)&wsh[r * 1032 + k] =
            *(const bf16x8*)(Whi + (size_t)(g * 16 + r) * 1024 + k);
    }

    int s = tid >> 2, dl = tid & 3;
    int d = g * 4 + dl;
    float creg = 0.f;           // register-resident cell state

    __syncthreads();

    const short* bhp = &wsh[l16 * 1032 + kbase + quad * 8];
    const short* blp = Wlo + (size_t)(g * 16 + l16) * 1024 + kbase + quad * 8;

    for (int t = 0; t < 32; t++) {
        const short* ah = H1hi + (size_t)t * 65536 + (size_t)l16 * 1024 + kbase + quad * 8;
        const short* al = H1lo + (size_t)t * 65536 + (size_t)l16 * 1024 + kbase + quad * 8;

        f32x4 acc[4];
        f32x4 z4 = {0.f, 0.f, 0.f, 0.f};
        acc[0] = z4; acc[1] = z4; acc[2] = z4; acc[3] = z4;

        #pragma unroll
        for (int i = 0; i < 8; i++) {
            int k = i * 32;
            bf16x8 Bh = *(const bf16x8*)(bhp + k);
            bf16x8 Bl = *(const bf16x8*)(blp + k);
            #pragma unroll
            for (int mt = 0; mt < 4; mt++) {
                bf16x8 Ah = *(const bf16x8*)(ah + mt * 16 * 1024 + k);
                bf16x8 Al = *(const bf16x8*)(al + mt * 16 * 1024 + k);
                acc[mt] = __builtin_amdgcn_mfma_f32_16x16x32_bf16(Ah, Bh, acc[mt], 0, 0, 0);
                acc[mt] = __builtin_amdgcn_mfma_f32_16x16x32_bf16(Al, Bh, acc[mt], 0, 0, 0);
                acc[mt] = __builtin_amdgcn_mfma_f32_16x16x32_bf16(Ah, Bl, acc[mt], 0, 0, 0);
            }
        }
        #pragma unroll
        for (int mt = 0; mt < 4; mt++)
            #pragma unroll
            for (int r = 0; r < 4; r++) {
                int sr = mt * 16 + quad * 4 + r;
                red[(w * 64 + sr) * 16 + l16] = acc[mt][r];
            }
        __syncthreads();

        float gi = 0.f, gf = 0.f, gg = 0.f, go = 0.f;
        #pragma unroll
        for (int w2 = 0; w2 < 4; w2++) {
            const float* rp = &red[(w2 * 64 + s) * 16 + dl * 4];
            gi += rp[0]; gf += rp[1]; gg += rp[2]; go += rp[3];
        }
        float4 xg = *(const float4*)(X12 + (size_t)t * 262144 + (size_t)s * 4096 + g * 16 + dl * 4);
        gi += xg.x; gf += xg.y; gg += xg.z; go += xg.w;
        float cn = sigm(gf) * creg + sigm(gi) * tanhf(gg);
        creg = cn;
        float hn = sigm(go) * tanhf(cn);
        short q = f2bf(hn);
        H1hi[(size_t)(t + 1) * 65536 + s * 1024 + d] = q;
        H1lo[(size_t)(t + 1) * 65536 + s * 1024 + d] = f2bf(hn - bf2f(q));
        H1f[(size_t)t * 65536 + s * 1024 + d] = hn;

        if (t != 31) grid_barrier(bcnt, bgen, 256u);
    }
}

// ---------------- fused layer-2 recurrence (persistent, own barrier) ---------
__global__ __launch_bounds__(256, 1) void lstm2_fused(
    const short* __restrict__ W, const float* __restrict__ X12,
    short* __restrict__ h2a, short* __restrict__ h2b,
    float* __restrict__ out,
    unsigned* __restrict__ bcnt, unsigned* __restrict__ bgen) {
    __shared__ short wsh[16 * 1032];
    __shared__ float red[4 * 64 * 16];

    int tid = threadIdx.x;
    int lane = tid & 63, w = tid >> 6;
    int quad = lane >> 4, l16 = lane & 15;
    int g = blockIdx.x;
    int kbase = w * 256;

    for (int i = tid; i < 2048; i += 256) {
        int r = i >> 7;
        int k = (i & 127) * 8;
        *(bf16x8*)&wsh[r * 1032 + k] =
            *(const bf16x8*)(W + (size_t)(g * 16 + r) * 1024 + k);
    }

    int s = tid >> 2, dl = tid & 3;
    int d = g * 4 + dl;
    float creg = 0.f;

    __syncthreads();

    const short* bp = &wsh[l16 * 1032 + kbase + quad * 8];

    for (int t = 0; t < 32; t++) {
        const short* Aprev = (t & 1) ? h2b : h2a;
        short* hout = (t & 1) ? h2a : h2b;
        const short* ar = Aprev + (size_t)l16 * 1024 + kbase + quad * 8;

        f32x4 acc[4];
        f32x4 z4 = {0.f, 0.f, 0.f, 0.f};
        acc[0] = z4; acc[1] = z4; acc[2] = z4; acc[3] = z4;

        #pragma unroll
        for (int i = 0; i < 8; i++) {
            int k = i * 32;
            bf16x8 b = *(const bf16x8*)(bp + k);
            #pragma unroll
            for (int mt = 0; mt < 4; mt++) {
                bf16x8 a = *(const bf16x8*)(ar + mt * 16 * 1024 + k);
                acc[mt] = __builtin_amdgcn_mfma_f32_16x16x32_bf16(a, b, acc[mt], 0, 0, 0);
            }
        }
        #pragma unroll
        for (int mt = 0; mt < 4; mt++)
            #pragma unroll
            for (int r = 0; r < 4; r++) {
                int sr = mt * 16 + quad * 4 + r;
                red[(w * 64 + sr) * 16 + l16] = acc[mt][r];
            }
        __syncthreads();

        float gi = 0.f, gf = 0.f, gg = 0.f, go = 0.f;
        #pragma unroll
        for (int w2 = 0; w2 < 4; w2++) {
            const float* rp = &red[(w2 * 64 + s) * 16 + dl * 4];
            gi += rp[0]; gf += rp[1]; gg += rp[2]; go += rp[3];
        }
        float4 xg = *(const float4*)(X12 + (size_t)t * 262144 + (size_t)s * 4096 + g * 16 + dl * 4);
        gi += xg.x; gf += xg.y; gg += xg.z; go += xg.w;
        float cn = sigm(gf) * creg + sigm(gi) * tanhf(gg);
        creg = cn;
        float hn = sigm(go) * tanhf(cn);
        hout[s * 1024 + d] = f2bf(hn);
        out[(size_t)t * 65536 + s * 1024 + d] = hn;

        if (t != 31) grid_barrier(bcnt, bgen, 256u);
    }
}

// ---------------- batched attention (fp32, unchanged) ----------------
__global__ __launch_bounds__(256) void attn_batch(
    const float* __restrict__ H1f, const float* __restrict__ F,
    short* __restrict__ Vhi, short* __restrict__ Vlo) {
    __shared__ float vs[4][4][1024];
    int n = blockIdx.x, tg = blockIdx.y;
    int tid = threadIdx.x, lane = tid & 63, w = tid >> 6;

    float h[4][16];
    #pragma unroll
    for (int tt = 0; tt < 4; tt++) {
        const float* hp = H1f + ((size_t)((tg * 4 + tt) * 64 + n)) * 1024 + lane * 16;
        #pragma unroll
        for (int j = 0; j < 4; j++) {
            float4 v = *(const float4*)(hp + j * 4);
            h[tt][j * 4 + 0] = v.x; h[tt][j * 4 + 1] = v.y;
            h[tt][j * 4 + 2] = v.z; h[tt][j * 4 + 3] = v.w;
        }
    }
    float vacc[4][16];
    #pragma unroll
    for (int tt = 0; tt < 4; tt++)
        #pragma unroll
        for (int j = 0; j < 16; j++) vacc[tt][j] = 0.f;

    const float* Fn = F + ((size_t)n * 196) * 1024 + lane * 16;
    for (int l = w; l < 196; l += 4) {
        const float* fr = Fn + (size_t)l * 1024;
        float f[16];
        #pragma unroll
        for (int j = 0; j < 4; j++) {
            float4 v = *(const float4*)(fr + j * 4);
            f[j * 4 + 0] = v.x; f[j * 4 + 1] = v.y;
            f[j * 4 + 2] = v.z; f[j * 4 + 3] = v.w;
        }
        float p[4] = {0.f, 0.f, 0.f, 0.f};
        #pragma unroll
        for (int tt = 0; tt < 4; tt++)
            #pragma unroll
            for (int j = 0; j < 16; j++) p[tt] += f[j] * h[tt][j];
        #pragma unroll
        for (int off = 32; off > 0; off >>= 1) {
            #pragma unroll
            for (int tt = 0; tt < 4; tt++) p[tt] += __shfl_xor(p[tt], off, 64);
        }
        #pragma unroll
        for (int tt = 0; tt < 4; tt++)
            #pragma unroll
            for (int j = 0; j < 16; j++) vacc[tt][j] += p[tt] * f[j];
    }
    #pragma unroll
    for (int tt = 0; tt < 4; tt++)
        #pragma unroll
        for (int j4 = 0; j4 < 4; j4++) {
            float4 v;
            v.x = vacc[tt][j4 * 4 + 0]; v.y = vacc[tt][j4 * 4 + 1];
            v.z = vacc[tt][j4 * 4 + 2]; v.w = vacc[tt][j4 * 4 + 3];
            *(float4*)&vs[w][tt][lane * 16 + j4 * 4] = v;
        }
    __syncthreads();
    int d0 = tid * 4;
    #pragma unroll
    for (int tt = 0; tt < 4; tt++) {
        float4 a = *(const float4*)&vs[0][tt][d0];
        float4 b = *(const float4*)&vs[1][tt][d0];
        float4 cc = *(const float4*)&vs[2][tt][d0];
        float4 e = *(const float4*)&vs[3][tt][d0];
        float sv[4];
        sv[0] = a.x + b.x + cc.x + e.x;
        sv[1] = a.y + b.y + cc.y + e.y;
        sv[2] = a.z + b.z + cc.z + e.z;
        sv[3] = a.w + b.w + cc.w + e.w;
        short4v b1, b2;
        #pragma unroll
        for (int e2 = 0; e2 < 4; e2++) {
            short q = f2bf(sv[e2]);
            b1[e2] = q;
            b2[e2] = f2bf(sv[e2] - bf2f(q));
        }
        size_t row = ((size_t)(tg * 4 + tt) * 64 + n) * 1024 + d0;
        *(short4v*)(Vhi + row) = b1;
        *(short4v*)(Vlo + row) = b2;
    }
}

// ---------------- host launch ----------------
extern "C" void kernel_launch(void* const* d_in, const int* in_sizes, int n_in,
                              void* d_out, int out_size, void* d_ws, size_t ws_size,
                              hipStream_t stream) {
    const int*   tokens = (const int*)d_in[0];
    const float* imgf   = (const float*)d_in[1];
    const float* emb    = (const float*)d_in[2];
    const float* w_ih1  = (const float*)d_in[3];
    const float* w_hh1  = (const float*)d_in[4];
    const float* b_ih1  = (const float*)d_in[5];
    const float* b_hh1  = (const float*)d_in[6];
    const float* w_ih2  = (const float*)d_in[7];
    const float* w_hh2  = (const float*)d_in[8];
    const float* b_ih2  = (const float*)d_in[9];
    const float* b_hh2  = (const float*)d_in[10];
    float* out = (float*)d_out;
    char* ws = (char*)d_ws;

    unsigned* bar1c = (unsigned*)(ws + OFF_C1);        // barrier vars, own lines
    unsigned* bar1g = (unsigned*)(ws + OFF_C1 + 64);
    unsigned* bar2c = (unsigned*)(ws + OFF_C1 + 128);
    unsigned* bar2g = (unsigned*)(ws + OFF_C1 + 192);
    short* h2a    = (short*)(ws + OFF_H2A);
    short* h2b    = (short*)(ws + OFF_H2B);
    short* H1hi   = (short*)(ws + OFF_H1HI);
    short* H1lo   = (short*)(ws + OFF_H1LO);
    float* H1f    = (float*)(ws + OFF_H1F);
    short* X0hi   = (short*)(ws + OFF_X0HI);
    short* X0lo   = (short*)(ws + OFF_X0LO);
    short* Vhi    = (short*)(ws + OFF_X0HI);   // alias (X0 dead after X1 GEMM)
    short* Vlo    = (short*)(ws + OFF_X0LO);
    float* bias1p = (float*)(ws + OFF_B1);
    float* bias2p = (float*)(ws + OFF_B2);
    short* whh1hi = (short*)(ws + OFF_WHH1HI);
    short* whh1lo = (short*)(ws + OFF_WHH1LO);
    short* wih1hi = (short*)(ws + OFF_WIH1HI);
    short* wih1lo = (short*)(ws + OFF_WIH1LO);
    short* whh2hi = (short*)(ws + OFF_WHH2HI);
    short* wvhi   = (short*)(ws + OFF_WVHI);
    short* wvlo   = (short*)(ws + OFF_WVLO);
    short* wh2hi  = (short*)(ws + OFF_WH2HI);
    float* X12    = (float*)(ws + OFF_X12);
    short* dump   = (short*)(ws + OFF_X12);    // prep-time scratch, overwritten later

    // prep (cell state register-resident; h states + barrier vars need zeroing)
    zero_ws<<<1, 256, 0, stream>>>((float4*)(ws + OFF_C1));      // barrier vars
    zero_ws<<<64, 256, 0, stream>>>((float4*)(ws + OFF_H2A));    // h2a,h2b
    zero_ws<<<32, 256, 0, stream>>>((float4*)(ws + OFF_H1HI));   // H1hi slot 0
    zero_ws<<<32, 256, 0, stream>>>((float4*)(ws + OFF_H1LO));   // H1lo slot 0
    perm_w_split<<<4096, 256, 0, stream>>>(w_hh1, whh1hi, whh1lo, 1024, 0);
    perm_w_split<<<4096, 256, 0, stream>>>(w_ih1, wih1hi, wih1lo, 1024, 0);
    perm_w_split<<<4096, 256, 0, stream>>>(w_hh2, whh2hi, dump, 1024, 0);
    perm_w_split<<<4096, 256, 0, stream>>>(w_ih2, wvhi, wvlo, 2048, 0);
    perm_w_split<<<4096, 256, 0, stream>>>(w_ih2, wh2hi, dump, 2048, 1024);
    bias_prep<<<16, 256, 0, stream>>>(b_ih1, b_hh1, b_ih2, b_hh2, bias1p, bias2p);
    gather_x0_split<<<2048, 256, 0, stream>>>(tokens, emb, X0hi, X0lo);

    // X1 = (X0hi+X0lo) @ (wih1hi+wih1lo)^T + bias1, triple-split, K=3072
    big_gemm<<<dim3(32, 16), 256, 0, stream>>>(
        X0hi, X0lo, X0hi, X0hi,
        wih1hi, wih1hi, wih1lo, wih1hi,
        bias1p, X12, 3072);

    // fused layer-1 recurrence (one normal launch, 32 steps inside)
    lstm1_fused<<<256, 256, 0, stream>>>(
        whh1hi, whh1lo, X12, H1hi, H1lo, H1f, bar1c, bar1g);

    // batched attention (fp32 in, compensated double-bf16 out)
    attn_batch<<<dim3(64, 8), 256, 0, stream>>>(H1f, imgf, Vhi, Vlo);

    // X2 = v@wv (triple-split) + h1@wh + bias2, K=4096
    big_gemm<<<dim3(32, 16), 256, 0, stream>>>(
        Vhi, Vlo, Vhi, H1hi + 65536,
        wvhi, wvhi, wvlo, wh2hi,
        bias2p, X12, 4096);

    // fused layer-2 recurrence (one normal launch, 32 steps inside)
    lstm2_fused<<<256, 256, 0, stream>>>(
        whh2hi, X12, h2a, h2b, out, bar2c, bar2g);
}

// Round 3
// 2529.678 us; speedup vs baseline: 2.0027x; 2.0027x over previous
//
#include <hip/hip_runtime.h>
#include <math.h>

// ---------------- types ----------------
typedef __attribute__((ext_vector_type(8))) short bf16x8;
typedef __attribute__((ext_vector_type(4))) short short4v;
typedef __attribute__((ext_vector_type(4))) float f32x4;

__device__ __forceinline__ float sigm(float x) { return 1.f / (1.f + expf(-x)); }

__device__ __forceinline__ float bf2f(short x) {
    unsigned u = ((unsigned)(unsigned short)x) << 16;
    float f; __builtin_memcpy(&f, &u, 4); return f;
}
__device__ __forceinline__ short f2bf(float f) {
    unsigned u; __builtin_memcpy(&u, &f, 4);
    unsigned r = (u + 0x7fffu + ((u >> 16) & 1u)) >> 16;
    return (short)r;
}

// ---------------- grid barrier v2: slot-store + relaxed all-gather -----------
// Arrival: block b stores (t+1) to its own 128B-spaced slot (relaxed agent
// store -> bypass, no cache op, no RMW). Wait: thread t polls slot t with
// RELAXED agent loads (no per-poll buffer_inv!). Coherence: exactly one
// release fence (wbL2) before arrival and one acquire fence (inv) after the
// gather, per block per step. Monotonic slot values -> re-entrant; slots
// zeroed in-graph each replay.
__device__ __forceinline__ void grid_barrier(unsigned* slots, unsigned tgt) {
    __syncthreads();                                     // all waves' stores drained to L2
    __builtin_amdgcn_fence(__ATOMIC_RELEASE, "agent");   // wbL2: publish to coherence point
    if (threadIdx.x == 0)
        __hip_atomic_store(slots + (size_t)blockIdx.x * 32, tgt,
                           __ATOMIC_RELAXED, __HIP_MEMORY_SCOPE_AGENT);
    unsigned* my = slots + (size_t)threadIdx.x * 32;
    while (__hip_atomic_load(my, __ATOMIC_RELAXED, __HIP_MEMORY_SCOPE_AGENT) < tgt)
        __builtin_amdgcn_s_sleep(8);
    __syncthreads();                                     // AND over all 256 slot conditions
    __builtin_amdgcn_fence(__ATOMIC_ACQUIRE, "agent");   // inv stale L1/L2 lines, once
}

// ---------------- workspace layout (byte offsets) ----------------
#define OFF_C1      0u           // barrier slots: 2 x 32KB (zeroed in-graph)
#define OFF_C2      262144u
#define OFF_H2A     524288u      // 64x1024 bf16  131072
#define OFF_H2B     655360u      // 64x1024 bf16  131072
#define OFF_H1HI    786432u      // 33 x 64x1024 bf16  4325376
#define OFF_H1LO    5111808u     // 33 x 64x1024 bf16  4325376
#define OFF_H1F     9437184u     // 32 x 64x1024 f32   8388608
#define OFF_X0HI    17825792u    // 2048x1024 bf16 4194304  (aliased by VHI later)
#define OFF_X0LO    22020096u    // 2048x1024 bf16 4194304  (aliased by VLO later)
#define OFF_B1      26214400u    // 4096 f32 16384
#define OFF_B2      26230784u    // 4096 f32 16384
#define OFF_WHH1HI  26247168u    // 4096x1024 bf16 8388608
#define OFF_WHH1LO  34635776u
#define OFF_WIH1HI  43024384u
#define OFF_WIH1LO  51412992u
#define OFF_WHH2HI  59801600u
#define OFF_WVHI    68190208u
#define OFF_WVLO    76578816u
#define OFF_WH2HI   84967424u
#define OFF_X12     93356032u    // 2048x4096 f32 33554432 (also lo-dump during prep)

// ---------------- prep kernels ----------------
__global__ __launch_bounds__(256) void zero_ws(float4* __restrict__ p) {
    int i = blockIdx.x * 256 + threadIdx.x;
    p[i] = make_float4(0.f, 0.f, 0.f, 0.f);
}

__global__ __launch_bounds__(256) void perm_w_split(const float* __restrict__ src,
                                                    short* __restrict__ hi,
                                                    short* __restrict__ lo,
                                                    int rs, int co) {
    int idx = blockIdx.x * 256 + threadIdx.x;   // 4096 blocks
    int jp = idx >> 8;
    int kq = idx & 255;
    int jsrc = (jp & 3) * 1024 + (jp >> 2);
    float4 v = *(const float4*)(src + (size_t)jsrc * rs + co + kq * 4);
    float a[4] = {v.x, v.y, v.z, v.w};
    short4v h, l;
    #pragma unroll
    for (int e = 0; e < 4; e++) {
        short q = f2bf(a[e]);
        h[e] = q;
        l[e] = f2bf(a[e] - bf2f(q));
    }
    *(short4v*)(hi + (size_t)jp * 1024 + kq * 4) = h;
    *(short4v*)(lo + (size_t)jp * 1024 + kq * 4) = l;
}

__global__ __launch_bounds__(256) void bias_prep(
    const float* __restrict__ bi1, const float* __restrict__ bh1,
    const float* __restrict__ bi2, const float* __restrict__ bh2,
    float* __restrict__ b1p, float* __restrict__ b2p) {
    int jp = blockIdx.x * 256 + threadIdx.x;     // 16 blocks
    int j = (jp & 3) * 1024 + (jp >> 2);
    b1p[jp] = bi1[j] + bh1[j];
    b2p[jp] = bi2[j] + bh2[j];
}

__global__ __launch_bounds__(256) void gather_x0_split(
    const int* __restrict__ tokens, const float* __restrict__ emb,
    short* __restrict__ hi, short* __restrict__ lo) {
    int idx = blockIdx.x * 256 + threadIdx.x;    // 2048 blocks
    int p = idx >> 8;
    int k0 = (idx & 255) * 4;
    int tok = tokens[p];
    float4 v = *(const float4*)(emb + (size_t)tok * 1024 + k0);
    float a[4] = {v.x, v.y, v.z, v.w};
    short4v h, l;
    #pragma unroll
    for (int e = 0; e < 4; e++) {
        short q = f2bf(a[e]);
        h[e] = q;
        l[e] = f2bf(a[e] - bf2f(q));
    }
    *(short4v*)(hi + (size_t)p * 1024 + k0) = h;
    *(short4v*)(lo + (size_t)p * 1024 + k0) = l;
}

// ---------------- big GEMM (unchanged) ----------------
__global__ __launch_bounds__(256) void big_gemm(
    const short* __restrict__ A0, const short* __restrict__ A1s,
    const short* __restrict__ A2s, const short* __restrict__ A3s,
    const short* __restrict__ B0, const short* __restrict__ B1s,
    const short* __restrict__ B2s, const short* __restrict__ B3s,
    const float* __restrict__ bias, float* __restrict__ C, int K) {
    __shared__ short As[128 * 40];
    __shared__ short Bs[128 * 40];
    int tid = threadIdx.x;
    int n0 = blockIdx.x * 128;
    int m0 = blockIdx.y * 128;
    int lane = tid & 63, w = tid >> 6;
    int wm = (w >> 1) * 64, wn = (w & 1) * 64;
    int quad = lane >> 4, l16 = lane & 15;
    int srow = tid >> 2;
    int skc = (tid & 3) * 8;

    f32x4 acc[4][4];
    f32x4 z4 = {0.f, 0.f, 0.f, 0.f};
    #pragma unroll
    for (int i = 0; i < 4; i++)
        #pragma unroll
        for (int j = 0; j < 4; j++) acc[i][j] = z4;

    for (int k0 = 0; k0 < K; k0 += 32) {
        int seg = k0 >> 10;
        const short* Ab = (seg == 0) ? A0 : (seg == 1) ? A1s : (seg == 2) ? A2s : A3s;
        const short* Bb = (seg == 0) ? B0 : (seg == 1) ? B1s : (seg == 2) ? B2s : B3s;
        int kk = (k0 & 1023) + skc;
        const short* ga = Ab + (size_t)(m0 + srow) * 1024 + kk;
        const short* gb = Bb + (size_t)(n0 + srow) * 1024 + kk;
        bf16x8 av0 = *(const bf16x8*)ga;
        bf16x8 av1 = *(const bf16x8*)(ga + 64 * 1024);
        bf16x8 bv0 = *(const bf16x8*)gb;
        bf16x8 bv1 = *(const bf16x8*)(gb + 64 * 1024);
        __syncthreads();
        *(bf16x8*)&As[srow * 40 + skc] = av0;
        *(bf16x8*)&As[(srow + 64) * 40 + skc] = av1;
        *(bf16x8*)&Bs[srow * 40 + skc] = bv0;
        *(bf16x8*)&Bs[(srow + 64) * 40 + skc] = bv1;
        __syncthreads();
        bf16x8 af[4], bfr[4];
        #pragma unroll
        for (int im = 0; im < 4; im++)
            af[im] = *(const bf16x8*)&As[(wm + im * 16 + l16) * 40 + quad * 8];
        #pragma unroll
        for (int in = 0; in < 4; in++)
            bfr[in] = *(const bf16x8*)&Bs[(wn + in * 16 + l16) * 40 + quad * 8];
        #pragma unroll
        for (int im = 0; im < 4; im++)
            #pragma unroll
            for (int in = 0; in < 4; in++)
                acc[im][in] = __builtin_amdgcn_mfma_f32_16x16x32_bf16(
                    af[im], bfr[in], acc[im][in], 0, 0, 0);
    }
    #pragma unroll
    for (int in = 0; in < 4; in++) {
        int j = n0 + wn + in * 16 + l16;
        float bsv = bias[j];
        #pragma unroll
        for (int im = 0; im < 4; im++) {
            #pragma unroll
            for (int r = 0; r < 4; r++) {
                int p = m0 + wm + im * 16 + quad * 4 + r;
                C[(size_t)p * 4096 + j] = acc[im][in][r] + bsv;
            }
        }
    }
}

// ---------------- fused layer-1 recurrence (persistent, own barrier) ---------
// 256 blocks x 256 thr. Block g owns gate-rows [g*16,g*16+16) of whh1.
// W-hi pinned in LDS (padded stride 1032 -> conflict-free); W-lo from global
// (L2/L3-resident). Cell state register-resident. LDS 49.4 KB -> 3 blocks/CU
// capacity, grid 256 = 1/CU -> always fully resident (no deadlock).
__global__ __launch_bounds__(256, 1) void lstm1_fused(
    const short* __restrict__ Whi, const short* __restrict__ Wlo,
    const float* __restrict__ X12,
    short* __restrict__ H1hi, short* __restrict__ H1lo,
    float* __restrict__ H1f,
    unsigned* __restrict__ slots) {
    __shared__ short wsh[16 * 1032];
    __shared__ float red[4 * 64 * 16];

    int tid = threadIdx.x;
    int lane = tid & 63, w = tid >> 6;
    int quad = lane >> 4, l16 = lane & 15;
    int g = blockIdx.x;
    int kbase = w * 256;

    // stage hi-weight slice into LDS once
    for (int i = tid; i < 2048; i += 256) {
        int r = i >> 7;
        int k = (i & 127) * 8;
        *(bf16x8*)&wsh[r * 1032 + k] =
            *(const bf16x8*)(Whi + (size_t)(g * 16 + r) * 1024 + k);
    }

    int s = tid >> 2, dl = tid & 3;
    int d = g * 4 + dl;
    float creg = 0.f;           // register-resident cell state

    __syncthreads();

    const short* bhp = &wsh[l16 * 1032 + kbase + quad * 8];
    const short* blp = Wlo + (size_t)(g * 16 + l16) * 1024 + kbase + quad * 8;

    for (int t = 0; t < 32; t++) {
        const short* ah = H1hi + (size_t)t * 65536 + (size_t)l16 * 1024 + kbase + quad * 8;
        const short* al = H1lo + (size_t)t * 65536 + (size_t)l16 * 1024 + kbase + quad * 8;

        f32x4 acc[4];
        f32x4 z4 = {0.f, 0.f, 0.f, 0.f};
        acc[0] = z4; acc[1] = z4; acc[2] = z4; acc[3] = z4;

        #pragma unroll
        for (int i = 0; i < 8; i++) {
            int k = i * 32;
            bf16x8 Bh = *(const bf16x8*)(bhp + k);
            bf16x8 Bl = *(const bf16x8*)(blp + k);
            #pragma unroll
            for (int mt = 0; mt < 4; mt++) {
                bf16x8 Ah = *(const bf16x8*)(ah + mt * 16 * 1024 + k);
                bf16x8 Al = *(const bf16x8*)(al + mt * 16 * 1024 + k);
                acc[mt] = __builtin_amdgcn_mfma_f32_16x16x32_bf16(Ah, Bh, acc[mt], 0, 0, 0);
                acc[mt] = __builtin_amdgcn_mfma_f32_16x16x32_bf16(Al, Bh, acc[mt], 0, 0, 0);
                acc[mt] = __builtin_amdgcn_mfma_f32_16x16x32_bf16(Ah, Bl, acc[mt], 0, 0, 0);
            }
        }
        #pragma unroll
        for (int mt = 0; mt < 4; mt++)
            #pragma unroll
            for (int r = 0; r < 4; r++) {
                int sr = mt * 16 + quad * 4 + r;
                red[(w * 64 + sr) * 16 + l16] = acc[mt][r];
            }
        __syncthreads();

        float gi = 0.f, gf = 0.f, gg = 0.f, go = 0.f;
        #pragma unroll
        for (int w2 = 0; w2 < 4; w2++) {
            const float* rp = &red[(w2 * 64 + s) * 16 + dl * 4];
            gi += rp[0]; gf += rp[1]; gg += rp[2]; go += rp[3];
        }
        float4 xg = *(const float4*)(X12 + (size_t)t * 262144 + (size_t)s * 4096 + g * 16 + dl * 4);
        gi += xg.x; gf += xg.y; gg += xg.z; go += xg.w;
        float cn = sigm(gf) * creg + sigm(gi) * tanhf(gg);
        creg = cn;
        float hn = sigm(go) * tanhf(cn);
        short q = f2bf(hn);
        H1hi[(size_t)(t + 1) * 65536 + s * 1024 + d] = q;
        H1lo[(size_t)(t + 1) * 65536 + s * 1024 + d] = f2bf(hn - bf2f(q));
        H1f[(size_t)t * 65536 + s * 1024 + d] = hn;

        if (t != 31) grid_barrier(slots, (unsigned)(t + 1));
    }
}

// ---------------- fused layer-2 recurrence (persistent, own barrier) ---------
__global__ __launch_bounds__(256, 1) void lstm2_fused(
    const short* __restrict__ W, const float* __restrict__ X12,
    short* __restrict__ h2a, short* __restrict__ h2b,
    float* __restrict__ out,
    unsigned* __restrict__ slots) {
    __shared__ short wsh[16 * 1032];
    __shared__ float red[4 * 64 * 16];

    int tid = threadIdx.x;
    int lane = tid & 63, w = tid >> 6;
    int quad = lane >> 4, l16 = lane & 15;
    int g = blockIdx.x;
    int kbase = w * 256;

    for (int i = tid; i < 2048; i += 256) {
        int r = i >> 7;
        int k = (i & 127) * 8;
        *(bf16x8*)&wsh[r * 1032 + k] =
            *(const bf16x8*)(W + (size_t)(g * 16 + r) * 1024 + k);
    }

    int s = tid >> 2, dl = tid & 3;
    int d = g * 4 + dl;
    float creg = 0.f;

    __syncthreads();

    const short* bp = &wsh[l16 * 1032 + kbase + quad * 8];

    for (int t = 0; t < 32; t++) {
        const short* Aprev = (t & 1) ? h2b : h2a;
        short* hout = (t & 1) ? h2a : h2b;
        const short* ar = Aprev + (size_t)l16 * 1024 + kbase + quad * 8;

        f32x4 acc[4];
        f32x4 z4 = {0.f, 0.f, 0.f, 0.f};
        acc[0] = z4; acc[1] = z4; acc[2] = z4; acc[3] = z4;

        #pragma unroll
        for (int i = 0; i < 8; i++) {
            int k = i * 32;
            bf16x8 b = *(const bf16x8*)(bp + k);
            #pragma unroll
            for (int mt = 0; mt < 4; mt++) {
                bf16x8 a = *(const bf16x8*)(ar + mt * 16 * 1024 + k);
                acc[mt] = __builtin_amdgcn_mfma_f32_16x16x32_bf16(a, b, acc[mt], 0, 0, 0);
            }
        }
        #pragma unroll
        for (int mt = 0; mt < 4; mt++)
            #pragma unroll
            for (int r = 0; r < 4; r++) {
                int sr = mt * 16 + quad * 4 + r;
                red[(w * 64 + sr) * 16 + l16] = acc[mt][r];
            }
        __syncthreads();

        float gi = 0.f, gf = 0.f, gg = 0.f, go = 0.f;
        #pragma unroll
        for (int w2 = 0; w2 < 4; w2++) {
            const float* rp = &red[(w2 * 64 + s) * 16 + dl * 4];
            gi += rp[0]; gf += rp[1]; gg += rp[2]; go += rp[3];
        }
        float4 xg = *(const float4*)(X12 + (size_t)t * 262144 + (size_t)s * 4096 + g * 16 + dl * 4);
        gi += xg.x; gf += xg.y; gg += xg.z; go += xg.w;
        float cn = sigm(gf) * creg + sigm(gi) * tanhf(gg);
        creg = cn;
        float hn = sigm(go) * tanhf(cn);
        hout[s * 1024 + d] = f2bf(hn);
        out[(size_t)t * 65536 + s * 1024 + d] = hn;

        if (t != 31) grid_barrier(slots, (unsigned)(t + 1));
    }
}

// ---------------- batched attention (fp32, unchanged) ----------------
__global__ __launch_bounds__(256) void attn_batch(
    const float* __restrict__ H1f, const float* __restrict__ F,
    short* __restrict__ Vhi, short* __restrict__ Vlo) {
    __shared__ float vs[4][4][1024];
    int n = blockIdx.x, tg = blockIdx.y;
    int tid = threadIdx.x, lane = tid & 63, w = tid >> 6;

    float h[4][16];
    #pragma unroll
    for (int tt = 0; tt < 4; tt++) {
        const float* hp = H1f + ((size_t)((tg * 4 + tt) * 64 + n)) * 1024 + lane * 16;
        #pragma unroll
        for (int j = 0; j < 4; j++) {
            float4 v = *(const float4*)(hp + j * 4);
            h[tt][j * 4 + 0] = v.x; h[tt][j * 4 + 1] = v.y;
            h[tt][j * 4 + 2] = v.z; h[tt][j * 4 + 3] = v.w;
        }
    }
    float vacc[4][16];
    #pragma unroll
    for (int tt = 0; tt < 4; tt++)
        #pragma unroll
        for (int j = 0; j < 16; j++) vacc[tt][j] = 0.f;

    const float* Fn = F + ((size_t)n * 196) * 1024 + lane * 16;
    for (int l = w; l < 196; l += 4) {
        const float* fr = Fn + (size_t)l * 1024;
        float f[16];
        #pragma unroll
        for (int j = 0; j < 4; j++) {
            float4 v = *(const float4*)(fr + j * 4);
            f[j * 4 + 0] = v.x; f[j * 4 + 1] = v.y;
            f[j * 4 + 2] = v.z; f[j * 4 + 3] = v.w;
        }
        float p[4] = {0.f, 0.f, 0.f, 0.f};
        #pragma unroll
        for (int tt = 0; tt < 4; tt++)
            #pragma unroll
            for (int j = 0; j < 16; j++) p[tt] += f[j] * h[tt][j];
        #pragma unroll
        for (int off = 32; off > 0; off >>= 1) {
            #pragma unroll
            for (int tt = 0; tt < 4; tt++) p[tt] += __shfl_xor(p[tt], off, 64);
        }
        #pragma unroll
        for (int tt = 0; tt < 4; tt++)
            #pragma unroll
            for (int j = 0; j < 16; j++) vacc[tt][j] += p[tt] * f[j];
    }
    #pragma unroll
    for (int tt = 0; tt < 4; tt++)
        #pragma unroll
        for (int j4 = 0; j4 < 4; j4++) {
            float4 v;
            v.x = vacc[tt][j4 * 4 + 0]; v.y = vacc[tt][j4 * 4 + 1];
            v.z = vacc[tt][j4 * 4 + 2]; v.w = vacc[tt][j4 * 4 + 3];
            *(float4*)&vs[w][tt][lane * 16 + j4 * 4] = v;
        }
    __syncthreads();
    int d0 = tid * 4;
    #pragma unroll
    for (int tt = 0; tt < 4; tt++) {
        float4 a = *(const float4*)&vs[0][tt][d0];
        float4 b = *(const float4*)&vs[1][tt][d0];
        float4 cc = *(const float4*)&vs[2][tt][d0];
        float4 e = *(const float4*)&vs[3][tt][d0];
        float sv[4];
        sv[0] = a.x + b.x + cc.x + e.x;
        sv[1] = a.y + b.y + cc.y + e.y;
        sv[2] = a.z + b.z + cc.z + e.z;
        sv[3] = a.w + b.w + cc.w + e.w;
        short4v b1, b2;
        #pragma unroll
        for (int e2 = 0; e2 < 4; e2++) {
            short q = f2bf(sv[e2]);
            b1[e2] = q;
            b2[e2] = f2bf(sv[e2] - bf2f(q));
        }
        size_t row = ((size_t)(tg * 4 + tt) * 64 + n) * 1024 + d0;
        *(short4v*)(Vhi + row) = b1;
        *(short4v*)(Vlo + row) = b2;
    }
}

// ---------------- host launch ----------------
extern "C" void kernel_launch(void* const* d_in, const int* in_sizes, int n_in,
                              void* d_out, int out_size, void* d_ws, size_t ws_size,
                              hipStream_t stream) {
    const int*   tokens = (const int*)d_in[0];
    const float* imgf   = (const float*)d_in[1];
    const float* emb    = (const float*)d_in[2];
    const float* w_ih1  = (const float*)d_in[3];
    const float* w_hh1  = (const float*)d_in[4];
    const float* b_ih1  = (const float*)d_in[5];
    const float* b_hh1  = (const float*)d_in[6];
    const float* w_ih2  = (const float*)d_in[7];
    const float* w_hh2  = (const float*)d_in[8];
    const float* b_ih2  = (const float*)d_in[9];
    const float* b_hh2  = (const float*)d_in[10];
    float* out = (float*)d_out;
    char* ws = (char*)d_ws;

    unsigned* slots1 = (unsigned*)(ws + OFF_C1);           // 256 x 128B = 32KB
    unsigned* slots2 = (unsigned*)(ws + OFF_C1 + 32768u);  // 256 x 128B = 32KB
    short* h2a    = (short*)(ws + OFF_H2A);
    short* h2b    = (short*)(ws + OFF_H2B);
    short* H1hi   = (short*)(ws + OFF_H1HI);
    short* H1lo   = (short*)(ws + OFF_H1LO);
    float* H1f    = (float*)(ws + OFF_H1F);
    short* X0hi   = (short*)(ws + OFF_X0HI);
    short* X0lo   = (short*)(ws + OFF_X0LO);
    short* Vhi    = (short*)(ws + OFF_X0HI);   // alias (X0 dead after X1 GEMM)
    short* Vlo    = (short*)(ws + OFF_X0LO);
    float* bias1p = (float*)(ws + OFF_B1);
    float* bias2p = (float*)(ws + OFF_B2);
    short* whh1hi = (short*)(ws + OFF_WHH1HI);
    short* whh1lo = (short*)(ws + OFF_WHH1LO);
    short* wih1hi = (short*)(ws + OFF_WIH1HI);
    short* wih1lo = (short*)(ws + OFF_WIH1LO);
    short* whh2hi = (short*)(ws + OFF_WHH2HI);
    short* wvhi   = (short*)(ws + OFF_WVHI);
    short* wvlo   = (short*)(ws + OFF_WVLO);
    short* wh2hi  = (short*)(ws + OFF_WH2HI);
    float* X12    = (float*)(ws + OFF_X12);
    short* dump   = (short*)(ws + OFF_X12);    // prep-time scratch, overwritten later

    // prep (cell state register-resident; h states + barrier slots need zeroing)
    zero_ws<<<16, 256, 0, stream>>>((float4*)(ws + OFF_C1));     // both slot arrays
    zero_ws<<<64, 256, 0, stream>>>((float4*)(ws + OFF_H2A));    // h2a,h2b
    zero_ws<<<32, 256, 0, stream>>>((float4*)(ws + OFF_H1HI));   // H1hi slot 0
    zero_ws<<<32, 256, 0, stream>>>((float4*)(ws + OFF_H1LO));   // H1lo slot 0
    perm_w_split<<<4096, 256, 0, stream>>>(w_hh1, whh1hi, whh1lo, 1024, 0);
    perm_w_split<<<4096, 256, 0, stream>>>(w_ih1, wih1hi, wih1lo, 1024, 0);
    perm_w_split<<<4096, 256, 0, stream>>>(w_hh2, whh2hi, dump, 1024, 0);
    perm_w_split<<<4096, 256, 0, stream>>>(w_ih2, wvhi, wvlo, 2048, 0);
    perm_w_split<<<4096, 256, 0, stream>>>(w_ih2, wh2hi, dump, 2048, 1024);
    bias_prep<<<16, 256, 0, stream>>>(b_ih1, b_hh1, b_ih2, b_hh2, bias1p, bias2p);
    gather_x0_split<<<2048, 256, 0, stream>>>(tokens, emb, X0hi, X0lo);

    // X1 = (X0hi+X0lo) @ (wih1hi+wih1lo)^T + bias1, triple-split, K=3072
    big_gemm<<<dim3(32, 16), 256, 0, stream>>>(
        X0hi, X0lo, X0hi, X0hi,
        wih1hi, wih1hi, wih1lo, wih1hi,
        bias1p, X12, 3072);

    // fused layer-1 recurrence (one normal launch, 32 steps inside)
    lstm1_fused<<<256, 256, 0, stream>>>(
        whh1hi, whh1lo, X12, H1hi, H1lo, H1f, slots1);

    // batched attention (fp32 in, compensated double-bf16 out)
    attn_batch<<<dim3(64, 8), 256, 0, stream>>>(H1f, imgf, Vhi, Vlo);

    // X2 = v@wv (triple-split) + h1@wh + bias2, K=4096
    big_gemm<<<dim3(32, 16), 256, 0, stream>>>(
        Vhi, Vlo, Vhi, H1hi + 65536,
        wvhi, wvhi, wvlo, wh2hi,
        bias2p, X12, 4096);

    // fused layer-2 recurrence (one normal launch, 32 steps inside)
    lstm2_fused<<<256, 256, 0, stream>>>(
        whh2hi, X12, h2a, h2b, out, slots2);
}

// Round 4
// 1113.140 us; speedup vs baseline: 4.5513x; 2.2726x over previous
//
#include <hip/hip_runtime.h>
#include <math.h>

// ---------------- types ----------------
typedef __attribute__((ext_vector_type(8))) short bf16x8;
typedef __attribute__((ext_vector_type(4))) short short4v;
typedef __attribute__((ext_vector_type(4))) float f32x4;

__device__ __forceinline__ float sigm(float x) { return 1.f / (1.f + expf(-x)); }

__device__ __forceinline__ float bf2f(short x) {
    unsigned u = ((unsigned)(unsigned short)x) << 16;
    float f; __builtin_memcpy(&f, &u, 4); return f;
}
__device__ __forceinline__ short f2bf(float f) {
    unsigned u; __builtin_memcpy(&u, &f, 4);
    unsigned r = (u + 0x7fffu + ((u >> 16) & 1u)) >> 16;
    return (short)r;
}

// ---------------- grid barrier v3: fence-free ----------------
// Correctness argument: all cross-block recurrence data (h-state) is written
// with agent-scope relaxed ATOMIC stores (global_store sc1 -> write-through
// past the per-XCD L2, lands at the IF-cache coherence point). Buffers are
// TIME-INDEXED, so no reader ever holds a stale L1/L2 line for an address it
// is about to read (first touch is after this barrier). Hence NO wbL2 /
// buffer_inv is needed -- the v2 barrier's per-step agent fences (the 30us/step
// cost) are dropped entirely.
//   __syncthreads() emits s_waitcnt vmcnt(0) per wave before s_barrier, so all
// sc1 stores are complete at IF before thread 0 publishes the slot value.
// Poll loads are agent-scope relaxed atomics (bypass L2 -> see remote stores).
__device__ __forceinline__ void grid_barrier(unsigned* slots, unsigned tgt) {
    __syncthreads();                 // all waves' sc1 stores acked at IF
    if (threadIdx.x == 0)
        __hip_atomic_store(slots + (size_t)blockIdx.x * 32, tgt,
                           __ATOMIC_RELAXED, __HIP_MEMORY_SCOPE_AGENT);
    unsigned* my = slots + (size_t)threadIdx.x * 32;
    while (__hip_atomic_load(my, __ATOMIC_RELAXED, __HIP_MEMORY_SCOPE_AGENT) < tgt)
        __builtin_amdgcn_s_sleep(8);
    __syncthreads();                 // AND over all 256 slot conditions
    asm volatile("" ::: "memory");   // compiler-only: no load hoisting above
}

// ---------------- workspace layout (byte offsets) ----------------
#define OFF_C1      0u           // barrier slots: 2 x 32KB (zeroed in-graph)
#define OFF_C2      262144u
#define OFF_H2A     524288u      // (unused now)
#define OFF_H2B     655360u      // (unused now)
#define OFF_H1HI    786432u      // 33 x 64x1024 bf16  4325376 (slot0 never read)
#define OFF_H1LO    5111808u     // 33 x 64x1024 bf16  4325376
#define OFF_H1F     9437184u     // 32 x 64x1024 f32 (lstm1 out) -> reused as
                                 // time-indexed H2 slots by lstm2 (4.2MB < 8.4MB)
#define OFF_X0HI    17825792u    // 2048x1024 bf16 4194304  (aliased by VHI later)
#define OFF_X0LO    22020096u    // 2048x1024 bf16 4194304  (aliased by VLO later)
#define OFF_B1      26214400u    // 4096 f32 16384
#define OFF_B2      26230784u    // 4096 f32 16384
#define OFF_WHH1HI  26247168u    // 4096x1024 bf16 8388608
#define OFF_WHH1LO  34635776u
#define OFF_WIH1HI  43024384u
#define OFF_WIH1LO  51412992u
#define OFF_WHH2HI  59801600u
#define OFF_WVHI    68190208u
#define OFF_WVLO    76578816u
#define OFF_WH2HI   84967424u
#define OFF_X12     93356032u    // 2048x4096 f32 33554432 (also lo-dump during prep)

// ---------------- prep kernels ----------------
__global__ __launch_bounds__(256) void zero_ws(float4* __restrict__ p) {
    int i = blockIdx.x * 256 + threadIdx.x;
    p[i] = make_float4(0.f, 0.f, 0.f, 0.f);
}

__global__ __launch_bounds__(256) void perm_w_split(const float* __restrict__ src,
                                                    short* __restrict__ hi,
                                                    short* __restrict__ lo,
                                                    int rs, int co) {
    int idx = blockIdx.x * 256 + threadIdx.x;   // 4096 blocks
    int jp = idx >> 8;
    int kq = idx & 255;
    int jsrc = (jp & 3) * 1024 + (jp >> 2);
    float4 v = *(const float4*)(src + (size_t)jsrc * rs + co + kq * 4);
    float a[4] = {v.x, v.y, v.z, v.w};
    short4v h, l;
    #pragma unroll
    for (int e = 0; e < 4; e++) {
        short q = f2bf(a[e]);
        h[e] = q;
        l[e] = f2bf(a[e] - bf2f(q));
    }
    *(short4v*)(hi + (size_t)jp * 1024 + kq * 4) = h;
    *(short4v*)(lo + (size_t)jp * 1024 + kq * 4) = l;
}

__global__ __launch_bounds__(256) void bias_prep(
    const float* __restrict__ bi1, const float* __restrict__ bh1,
    const float* __restrict__ bi2, const float* __restrict__ bh2,
    float* __restrict__ b1p, float* __restrict__ b2p) {
    int jp = blockIdx.x * 256 + threadIdx.x;     // 16 blocks
    int j = (jp & 3) * 1024 + (jp >> 2);
    b1p[jp] = bi1[j] + bh1[j];
    b2p[jp] = bi2[j] + bh2[j];
}

__global__ __launch_bounds__(256) void gather_x0_split(
    const int* __restrict__ tokens, const float* __restrict__ emb,
    short* __restrict__ hi, short* __restrict__ lo) {
    int idx = blockIdx.x * 256 + threadIdx.x;    // 2048 blocks
    int p = idx >> 8;
    int k0 = (idx & 255) * 4;
    int tok = tokens[p];
    float4 v = *(const float4*)(emb + (size_t)tok * 1024 + k0);
    float a[4] = {v.x, v.y, v.z, v.w};
    short4v h, l;
    #pragma unroll
    for (int e = 0; e < 4; e++) {
        short q = f2bf(a[e]);
        h[e] = q;
        l[e] = f2bf(a[e] - bf2f(q));
    }
    *(short4v*)(hi + (size_t)p * 1024 + k0) = h;
    *(short4v*)(lo + (size_t)p * 1024 + k0) = l;
}

// ---------------- big GEMM (unchanged) ----------------
__global__ __launch_bounds__(256) void big_gemm(
    const short* __restrict__ A0, const short* __restrict__ A1s,
    const short* __restrict__ A2s, const short* __restrict__ A3s,
    const short* __restrict__ B0, const short* __restrict__ B1s,
    const short* __restrict__ B2s, const short* __restrict__ B3s,
    const float* __restrict__ bias, float* __restrict__ C, int K) {
    __shared__ short As[128 * 40];
    __shared__ short Bs[128 * 40];
    int tid = threadIdx.x;
    int n0 = blockIdx.x * 128;
    int m0 = blockIdx.y * 128;
    int lane = tid & 63, w = tid >> 6;
    int wm = (w >> 1) * 64, wn = (w & 1) * 64;
    int quad = lane >> 4, l16 = lane & 15;
    int srow = tid >> 2;
    int skc = (tid & 3) * 8;

    f32x4 acc[4][4];
    f32x4 z4 = {0.f, 0.f, 0.f, 0.f};
    #pragma unroll
    for (int i = 0; i < 4; i++)
        #pragma unroll
        for (int j = 0; j < 4; j++) acc[i][j] = z4;

    for (int k0 = 0; k0 < K; k0 += 32) {
        int seg = k0 >> 10;
        const short* Ab = (seg == 0) ? A0 : (seg == 1) ? A1s : (seg == 2) ? A2s : A3s;
        const short* Bb = (seg == 0) ? B0 : (seg == 1) ? B1s : (seg == 2) ? B2s : B3s;
        int kk = (k0 & 1023) + skc;
        const short* ga = Ab + (size_t)(m0 + srow) * 1024 + kk;
        const short* gb = Bb + (size_t)(n0 + srow) * 1024 + kk;
        bf16x8 av0 = *(const bf16x8*)ga;
        bf16x8 av1 = *(const bf16x8*)(ga + 64 * 1024);
        bf16x8 bv0 = *(const bf16x8*)gb;
        bf16x8 bv1 = *(const bf16x8*)(gb + 64 * 1024);
        __syncthreads();
        *(bf16x8*)&As[srow * 40 + skc] = av0;
        *(bf16x8*)&As[(srow + 64) * 40 + skc] = av1;
        *(bf16x8*)&Bs[srow * 40 + skc] = bv0;
        *(bf16x8*)&Bs[(srow + 64) * 40 + skc] = bv1;
        __syncthreads();
        bf16x8 af[4], bfr[4];
        #pragma unroll
        for (int im = 0; im < 4; im++)
            af[im] = *(const bf16x8*)&As[(wm + im * 16 + l16) * 40 + quad * 8];
        #pragma unroll
        for (int in = 0; in < 4; in++)
            bfr[in] = *(const bf16x8*)&Bs[(wn + in * 16 + l16) * 40 + quad * 8];
        #pragma unroll
        for (int im = 0; im < 4; im++)
            #pragma unroll
            for (int in = 0; in < 4; in++)
                acc[im][in] = __builtin_amdgcn_mfma_f32_16x16x32_bf16(
                    af[im], bfr[in], acc[im][in], 0, 0, 0);
    }
    #pragma unroll
    for (int in = 0; in < 4; in++) {
        int j = n0 + wn + in * 16 + l16;
        float bsv = bias[j];
        #pragma unroll
        for (int im = 0; im < 4; im++) {
            #pragma unroll
            for (int r = 0; r < 4; r++) {
                int p = m0 + wm + im * 16 + quad * 4 + r;
                C[(size_t)p * 4096 + j] = acc[im][in][r] + bsv;
            }
        }
    }
}

// ---------------- fused layer-1 recurrence (persistent, fence-free) ----------
// 256 blocks x 256 thr. Block g owns gate-rows [g*16,g*16+16) of whh1.
// W-hi pinned in LDS; W-lo from global (stays L2-resident now that there is no
// per-step buffer_inv). Cell state register-resident. h written via sc1
// (agent-scope relaxed atomic) stores; H1 slots time-indexed; t=0 skips the
// h@W MFMA entirely (h1[0]=0), so slot 0 is never read or zeroed.
__global__ __launch_bounds__(256, 1) void lstm1_fused(
    const short* __restrict__ Whi, const short* __restrict__ Wlo,
    const float* __restrict__ X12,
    short* __restrict__ H1hi, short* __restrict__ H1lo,
    float* __restrict__ H1f,
    unsigned* __restrict__ slots) {
    __shared__ short wsh[16 * 1032];
    __shared__ float red[4 * 64 * 16];

    int tid = threadIdx.x;
    int lane = tid & 63, w = tid >> 6;
    int quad = lane >> 4, l16 = lane & 15;
    int g = blockIdx.x;
    int kbase = w * 256;

    // stage hi-weight slice into LDS once
    for (int i = tid; i < 2048; i += 256) {
        int r = i >> 7;
        int k = (i & 127) * 8;
        *(bf16x8*)&wsh[r * 1032 + k] =
            *(const bf16x8*)(Whi + (size_t)(g * 16 + r) * 1024 + k);
    }

    int s = tid >> 2, dl = tid & 3;
    int d = g * 4 + dl;
    float creg = 0.f;           // register-resident cell state

    __syncthreads();

    const short* bhp = &wsh[l16 * 1032 + kbase + quad * 8];
    const short* blp = Wlo + (size_t)(g * 16 + l16) * 1024 + kbase + quad * 8;

    for (int t = 0; t < 32; t++) {
        f32x4 acc[4];
        f32x4 z4 = {0.f, 0.f, 0.f, 0.f};
        acc[0] = z4; acc[1] = z4; acc[2] = z4; acc[3] = z4;

        if (t > 0) {   // h1[0] == 0 -> skip MFMA at t=0
            const short* ah = H1hi + (size_t)t * 65536 + (size_t)l16 * 1024 + kbase + quad * 8;
            const short* al = H1lo + (size_t)t * 65536 + (size_t)l16 * 1024 + kbase + quad * 8;
            #pragma unroll
            for (int i = 0; i < 8; i++) {
                int k = i * 32;
                bf16x8 Bh = *(const bf16x8*)(bhp + k);
                bf16x8 Bl = *(const bf16x8*)(blp + k);
                #pragma unroll
                for (int mt = 0; mt < 4; mt++) {
                    bf16x8 Ah = *(const bf16x8*)(ah + mt * 16 * 1024 + k);
                    bf16x8 Al = *(const bf16x8*)(al + mt * 16 * 1024 + k);
                    acc[mt] = __builtin_amdgcn_mfma_f32_16x16x32_bf16(Ah, Bh, acc[mt], 0, 0, 0);
                    acc[mt] = __builtin_amdgcn_mfma_f32_16x16x32_bf16(Al, Bh, acc[mt], 0, 0, 0);
                    acc[mt] = __builtin_amdgcn_mfma_f32_16x16x32_bf16(Ah, Bl, acc[mt], 0, 0, 0);
                }
            }
        }
        #pragma unroll
        for (int mt = 0; mt < 4; mt++)
            #pragma unroll
            for (int r = 0; r < 4; r++) {
                int sr = mt * 16 + quad * 4 + r;
                red[(w * 64 + sr) * 16 + l16] = acc[mt][r];
            }
        __syncthreads();

        float gi = 0.f, gf = 0.f, gg = 0.f, go = 0.f;
        #pragma unroll
        for (int w2 = 0; w2 < 4; w2++) {
            const float* rp = &red[(w2 * 64 + s) * 16 + dl * 4];
            gi += rp[0]; gf += rp[1]; gg += rp[2]; go += rp[3];
        }
        float4 xg = *(const float4*)(X12 + (size_t)t * 262144 + (size_t)s * 4096 + g * 16 + dl * 4);
        gi += xg.x; gf += xg.y; gg += xg.z; go += xg.w;
        float cn = sigm(gf) * creg + sigm(gi) * tanhf(gg);
        creg = cn;
        float hn = sigm(go) * tanhf(cn);
        short q = f2bf(hn);
        short ql = f2bf(hn - bf2f(q));
        // cross-block recurrence state: write-through (sc1) stores
        __hip_atomic_store(&H1hi[(size_t)(t + 1) * 65536 + s * 1024 + d], q,
                           __ATOMIC_RELAXED, __HIP_MEMORY_SCOPE_AGENT);
        __hip_atomic_store(&H1lo[(size_t)(t + 1) * 65536 + s * 1024 + d], ql,
                           __ATOMIC_RELAXED, __HIP_MEMORY_SCOPE_AGENT);
        // consumed only by later dispatches (attn) -> plain store is fine
        H1f[(size_t)t * 65536 + s * 1024 + d] = hn;

        if (t != 31) grid_barrier(slots, (unsigned)(t + 1));
    }
}

// ---------------- fused layer-2 recurrence (persistent, fence-free) ----------
// H2 is TIME-INDEXED (33 slots, lives in the dead H1F region) so the
// fence-free protocol applies; t=0 skips MFMA (h2[0]=0).
__global__ __launch_bounds__(256, 1) void lstm2_fused(
    const short* __restrict__ W, const float* __restrict__ X12,
    short* __restrict__ H2,
    float* __restrict__ out,
    unsigned* __restrict__ slots) {
    __shared__ short wsh[16 * 1032];
    __shared__ float red[4 * 64 * 16];

    int tid = threadIdx.x;
    int lane = tid & 63, w = tid >> 6;
    int quad = lane >> 4, l16 = lane & 15;
    int g = blockIdx.x;
    int kbase = w * 256;

    for (int i = tid; i < 2048; i += 256) {
        int r = i >> 7;
        int k = (i & 127) * 8;
        *(bf16x8*)&wsh[r * 1032 + k] =
            *(const bf16x8*)(W + (size_t)(g * 16 + r) * 1024 + k);
    }

    int s = tid >> 2, dl = tid & 3;
    int d = g * 4 + dl;
    float creg = 0.f;

    __syncthreads();

    const short* bp = &wsh[l16 * 1032 + kbase + quad * 8];

    for (int t = 0; t < 32; t++) {
        f32x4 acc[4];
        f32x4 z4 = {0.f, 0.f, 0.f, 0.f};
        acc[0] = z4; acc[1] = z4; acc[2] = z4; acc[3] = z4;

        if (t > 0) {   // h2[0] == 0 -> skip MFMA at t=0
            const short* ar = H2 + (size_t)t * 65536 + (size_t)l16 * 1024 + kbase + quad * 8;
            #pragma unroll
            for (int i = 0; i < 8; i++) {
                int k = i * 32;
                bf16x8 b = *(const bf16x8*)(bp + k);
                #pragma unroll
                for (int mt = 0; mt < 4; mt++) {
                    bf16x8 a = *(const bf16x8*)(ar + mt * 16 * 1024 + k);
                    acc[mt] = __builtin_amdgcn_mfma_f32_16x16x32_bf16(a, b, acc[mt], 0, 0, 0);
                }
            }
        }
        #pragma unroll
        for (int mt = 0; mt < 4; mt++)
            #pragma unroll
            for (int r = 0; r < 4; r++) {
                int sr = mt * 16 + quad * 4 + r;
                red[(w * 64 + sr) * 16 + l16] = acc[mt][r];
            }
        __syncthreads();

        float gi = 0.f, gf = 0.f, gg = 0.f, go = 0.f;
        #pragma unroll
        for (int w2 = 0; w2 < 4; w2++) {
            const float* rp = &red[(w2 * 64 + s) * 16 + dl * 4];
            gi += rp[0]; gf += rp[1]; gg += rp[2]; go += rp[3];
        }
        float4 xg = *(const float4*)(X12 + (size_t)t * 262144 + (size_t)s * 4096 + g * 16 + dl * 4);
        gi += xg.x; gf += xg.y; gg += xg.z; go += xg.w;
        float cn = sigm(gf) * creg + sigm(gi) * tanhf(gg);
        creg = cn;
        float hn = sigm(go) * tanhf(cn);
        __hip_atomic_store(&H2[(size_t)(t + 1) * 65536 + s * 1024 + d], f2bf(hn),
                           __ATOMIC_RELAXED, __HIP_MEMORY_SCOPE_AGENT);
        out[(size_t)t * 65536 + s * 1024 + d] = hn;   // host-visible after dispatch

        if (t != 31) grid_barrier(slots, (unsigned)(t + 1));
    }
}

// ---------------- batched attention (fp32, unchanged) ----------------
__global__ __launch_bounds__(256) void attn_batch(
    const float* __restrict__ H1f, const float* __restrict__ F,
    short* __restrict__ Vhi, short* __restrict__ Vlo) {
    __shared__ float vs[4][4][1024];
    int n = blockIdx.x, tg = blockIdx.y;
    int tid = threadIdx.x, lane = tid & 63, w = tid >> 6;

    float h[4][16];
    #pragma unroll
    for (int tt = 0; tt < 4; tt++) {
        const float* hp = H1f + ((size_t)((tg * 4 + tt) * 64 + n)) * 1024 + lane * 16;
        #pragma unroll
        for (int j = 0; j < 4; j++) {
            float4 v = *(const float4*)(hp + j * 4);
            h[tt][j * 4 + 0] = v.x; h[tt][j * 4 + 1] = v.y;
            h[tt][j * 4 + 2] = v.z; h[tt][j * 4 + 3] = v.w;
        }
    }
    float vacc[4][16];
    #pragma unroll
    for (int tt = 0; tt < 4; tt++)
        #pragma unroll
        for (int j = 0; j < 16; j++) vacc[tt][j] = 0.f;

    const float* Fn = F + ((size_t)n * 196) * 1024 + lane * 16;
    for (int l = w; l < 196; l += 4) {
        const float* fr = Fn + (size_t)l * 1024;
        float f[16];
        #pragma unroll
        for (int j = 0; j < 4; j++) {
            float4 v = *(const float4*)(fr + j * 4);
            f[j * 4 + 0] = v.x; f[j * 4 + 1] = v.y;
            f[j * 4 + 2] = v.z; f[j * 4 + 3] = v.w;
        }
        float p[4] = {0.f, 0.f, 0.f, 0.f};
        #pragma unroll
        for (int tt = 0; tt < 4; tt++)
            #pragma unroll
            for (int j = 0; j < 16; j++) p[tt] += f[j] * h[tt][j];
        #pragma unroll
        for (int off = 32; off > 0; off >>= 1) {
            #pragma unroll
            for (int tt = 0; tt < 4; tt++) p[tt] += __shfl_xor(p[tt], off, 64);
        }
        #pragma unroll
        for (int tt = 0; tt < 4; tt++)
            #pragma unroll
            for (int j = 0; j < 16; j++) vacc[tt][j] += p[tt] * f[j];
    }
    #pragma unroll
    for (int tt = 0; tt < 4; tt++)
        #pragma unroll
        for (int j4 = 0; j4 < 4; j4++) {
            float4 v;
            v.x = vacc[tt][j4 * 4 + 0]; v.y = vacc[tt][j4 * 4 + 1];
            v.z = vacc[tt][j4 * 4 + 2]; v.w = vacc[tt][j4 * 4 + 3];
            *(float4*)&vs[w][tt][lane * 16 + j4 * 4] = v;
        }
    __syncthreads();
    int d0 = tid * 4;
    #pragma unroll
    for (int tt = 0; tt < 4; tt++) {
        float4 a = *(const float4*)&vs[0][tt][d0];
        float4 b = *(const float4*)&vs[1][tt][d0];
        float4 cc = *(const float4*)&vs[2][tt][d0];
        float4 e = *(const float4*)&vs[3][tt][d0];
        float sv[4];
        sv[0] = a.x + b.x + cc.x + e.x;
        sv[1] = a.y + b.y + cc.y + e.y;
        sv[2] = a.z + b.z + cc.z + e.z;
        sv[3] = a.w + b.w + cc.w + e.w;
        short4v b1, b2;
        #pragma unroll
        for (int e2 = 0; e2 < 4; e2++) {
            short q = f2bf(sv[e2]);
            b1[e2] = q;
            b2[e2] = f2bf(sv[e2] - bf2f(q));
        }
        size_t row = ((size_t)(tg * 4 + tt) * 64 + n) * 1024 + d0;
        *(short4v*)(Vhi + row) = b1;
        *(short4v*)(Vlo + row) = b2;
    }
}

// ---------------- host launch ----------------
extern "C" void kernel_launch(void* const* d_in, const int* in_sizes, int n_in,
                              void* d_out, int out_size, void* d_ws, size_t ws_size,
                              hipStream_t stream) {
    const int*   tokens = (const int*)d_in[0];
    const float* imgf   = (const float*)d_in[1];
    const float* emb    = (const float*)d_in[2];
    const float* w_ih1  = (const float*)d_in[3];
    const float* w_hh1  = (const float*)d_in[4];
    const float* b_ih1  = (const float*)d_in[5];
    const float* b_hh1  = (const float*)d_in[6];
    const float* w_ih2  = (const float*)d_in[7];
    const float* w_hh2  = (const float*)d_in[8];
    const float* b_ih2  = (const float*)d_in[9];
    const float* b_hh2  = (const float*)d_in[10];
    float* out = (float*)d_out;
    char* ws = (char*)d_ws;

    unsigned* slots1 = (unsigned*)(ws + OFF_C1);           // 256 x 128B = 32KB
    unsigned* slots2 = (unsigned*)(ws + OFF_C1 + 32768u);  // 256 x 128B = 32KB
    short* H1hi   = (short*)(ws + OFF_H1HI);
    short* H1lo   = (short*)(ws + OFF_H1LO);
    float* H1f    = (float*)(ws + OFF_H1F);
    short* H2     = (short*)(ws + OFF_H1F);    // time-indexed h2 slots (after attn)
    short* X0hi   = (short*)(ws + OFF_X0HI);
    short* X0lo   = (short*)(ws + OFF_X0LO);
    short* Vhi    = (short*)(ws + OFF_X0HI);   // alias (X0 dead after X1 GEMM)
    short* Vlo    = (short*)(ws + OFF_X0LO);
    float* bias1p = (float*)(ws + OFF_B1);
    float* bias2p = (float*)(ws + OFF_B2);
    short* whh1hi = (short*)(ws + OFF_WHH1HI);
    short* whh1lo = (short*)(ws + OFF_WHH1LO);
    short* wih1hi = (short*)(ws + OFF_WIH1HI);
    short* wih1lo = (short*)(ws + OFF_WIH1LO);
    short* whh2hi = (short*)(ws + OFF_WHH2HI);
    short* wvhi   = (short*)(ws + OFF_WVHI);
    short* wvlo   = (short*)(ws + OFF_WVLO);
    short* wh2hi  = (short*)(ws + OFF_WH2HI);
    float* X12    = (float*)(ws + OFF_X12);
    short* dump   = (short*)(ws + OFF_X12);    // prep-time scratch, overwritten later

    // prep (cell state register-resident; t=0 skips h@W -> no h-slot zeroing;
    // only the barrier slot arrays need zeroing each replay)
    zero_ws<<<16, 256, 0, stream>>>((float4*)(ws + OFF_C1));     // both slot arrays
    perm_w_split<<<4096, 256, 0, stream>>>(w_hh1, whh1hi, whh1lo, 1024, 0);
    perm_w_split<<<4096, 256, 0, stream>>>(w_ih1, wih1hi, wih1lo, 1024, 0);
    perm_w_split<<<4096, 256, 0, stream>>>(w_hh2, whh2hi, dump, 1024, 0);
    perm_w_split<<<4096, 256, 0, stream>>>(w_ih2, wvhi, wvlo, 2048, 0);
    perm_w_split<<<4096, 256, 0, stream>>>(w_ih2, wh2hi, dump, 2048, 1024);
    bias_prep<<<16, 256, 0, stream>>>(b_ih1, b_hh1, b_ih2, b_hh2, bias1p, bias2p);
    gather_x0_split<<<2048, 256, 0, stream>>>(tokens, emb, X0hi, X0lo);

    // X1 = (X0hi+X0lo) @ (wih1hi+wih1lo)^T + bias1, triple-split, K=3072
    big_gemm<<<dim3(32, 16), 256, 0, stream>>>(
        X0hi, X0lo, X0hi, X0hi,
        wih1hi, wih1hi, wih1lo, wih1hi,
        bias1p, X12, 3072);

    // fused layer-1 recurrence (one normal launch, 32 steps inside)
    lstm1_fused<<<256, 256, 0, stream>>>(
        whh1hi, whh1lo, X12, H1hi, H1lo, H1f, slots1);

    // batched attention (fp32 in, compensated double-bf16 out)
    attn_batch<<<dim3(64, 8), 256, 0, stream>>>(H1f, imgf, Vhi, Vlo);

    // X2 = v@wv (triple-split) + h1@wh + bias2, K=4096
    big_gemm<<<dim3(32, 16), 256, 0, stream>>>(
        Vhi, Vlo, Vhi, H1hi + 65536,
        wvhi, wvhi, wvlo, wh2hi,
        bias2p, X12, 4096);

    // fused layer-2 recurrence (one normal launch, 32 steps inside)
    lstm2_fused<<<256, 256, 0, stream>>>(
        whh2hi, X12, H2, out, slots2);
}

// Round 6
// 1042.998 us; speedup vs baseline: 4.8574x; 1.0672x over previous
//
#include <hip/hip_runtime.h>
#include <math.h>

// ---------------- types ----------------
typedef __attribute__((ext_vector_type(8))) short bf16x8;
typedef __attribute__((ext_vector_type(4))) short short4v;
typedef __attribute__((ext_vector_type(4))) float f32x4;

__device__ __forceinline__ float sigm(float x) { return 1.f / (1.f + expf(-x)); }

__device__ __forceinline__ float bf2f(short x) {
    unsigned u = ((unsigned)(unsigned short)x) << 16;
    float f; __builtin_memcpy(&f, &u, 4); return f;
}
__device__ __forceinline__ short f2bf(float f) {
    unsigned u; __builtin_memcpy(&u, &f, 4);
    unsigned r = (u + 0x7fffu + ((u >> 16) & 1u)) >> 16;
    return (short)r;
}

// ---------------- barrier v5: hierarchical, system-scope, ~500 pollers -------
// v4 (agent polls): stale L2 lines -> eviction-limited (~8us/step).
// v5 (system polls, all 65536 threads): IF-fabric saturation -> hang.
// Fix: two-phase tree. Arrival = per-block slot store (system relaxed,
// write-through, no cache maintenance). Aggregate = block 0's 256 threads
// poll one slot each, then one release-word store. Wait = thread 0 per block
// polls the single release word. Pollers: 256 + 255 ~= 511. All values
// monotonic (t+1); slots zeroed via system-scope stores each replay.
__device__ __forceinline__ unsigned sys_ld(const unsigned* p) {
    return __hip_atomic_load(p, __ATOMIC_RELAXED, __HIP_MEMORY_SCOPE_SYSTEM);
}
__device__ __forceinline__ void sys_st(unsigned* p, unsigned v) {
    __hip_atomic_store(p, v, __ATOMIC_RELAXED, __HIP_MEMORY_SCOPE_SYSTEM);
}

// ---------------- workspace layout (byte offsets) ----------------
#define OFF_C1      0u           // barrier region 128KB (zeroed in-graph):
                                 // arrive1@0 (32KB), release1@32768,
                                 // arrive2@65536 (32KB), release2@98304
#define OFF_C2      262144u
#define OFF_H1HI    786432u      // 33 x 64x1024 bf16  4325376 (slot0 never read)
#define OFF_H1LO    5111808u     // 33 x 64x1024 bf16  4325376
#define OFF_H1F     9437184u     // 32 x 64x1024 f32 (lstm1 out) -> reused as
                                 // time-indexed H2 slots by lstm2
#define OFF_X0HI    17825792u    // 2048x1024 bf16 4194304  (aliased by VHI later)
#define OFF_X0LO    22020096u    // 2048x1024 bf16 4194304  (aliased by VLO later)
#define OFF_B1      26214400u    // 4096 f32 16384
#define OFF_B2      26230784u    // 4096 f32 16384
#define OFF_WHH1HI  26247168u    // 4096x1024 bf16 8388608
#define OFF_WHH1LO  34635776u
#define OFF_WIH1HI  43024384u
#define OFF_WIH1LO  51412992u
#define OFF_WHH2HI  59801600u
#define OFF_WVHI    68190208u
#define OFF_WVLO    76578816u
#define OFF_WH2HI   84967424u
#define OFF_X12     93356032u    // 2048x4096 f32 33554432 (also lo-dump during prep)

// ---------------- prep kernels ----------------
__global__ __launch_bounds__(256) void zero_ws(float4* __restrict__ p) {
    int i = blockIdx.x * 256 + threadIdx.x;
    p[i] = make_float4(0.f, 0.f, 0.f, 0.f);
}

// slot region must be zeroed with SYSTEM-scope (cache-bypass) stores so the
// system-scope polls in the fused kernels are guaranteed to observe the zeros.
__global__ __launch_bounds__(256) void zero_slots(unsigned* __restrict__ p) {
    int i = blockIdx.x * 256 + threadIdx.x;   // 128 blocks -> 32768 u32 = 128KB
    __hip_atomic_store(p + i, 0u, __ATOMIC_RELAXED, __HIP_MEMORY_SCOPE_SYSTEM);
}

__global__ __launch_bounds__(256) void perm_w_split(const float* __restrict__ src,
                                                    short* __restrict__ hi,
                                                    short* __restrict__ lo,
                                                    int rs, int co) {
    int idx = blockIdx.x * 256 + threadIdx.x;   // 4096 blocks
    int jp = idx >> 8;
    int kq = idx & 255;
    int jsrc = (jp & 3) * 1024 + (jp >> 2);
    float4 v = *(const float4*)(src + (size_t)jsrc * rs + co + kq * 4);
    float a[4] = {v.x, v.y, v.z, v.w};
    short4v h, l;
    #pragma unroll
    for (int e = 0; e < 4; e++) {
        short q = f2bf(a[e]);
        h[e] = q;
        l[e] = f2bf(a[e] - bf2f(q));
    }
    *(short4v*)(hi + (size_t)jp * 1024 + kq * 4) = h;
    *(short4v*)(lo + (size_t)jp * 1024 + kq * 4) = l;
}

__global__ __launch_bounds__(256) void bias_prep(
    const float* __restrict__ bi1, const float* __restrict__ bh1,
    const float* __restrict__ bi2, const float* __restrict__ bh2,
    float* __restrict__ b1p, float* __restrict__ b2p) {
    int jp = blockIdx.x * 256 + threadIdx.x;     // 16 blocks
    int j = (jp & 3) * 1024 + (jp >> 2);
    b1p[jp] = bi1[j] + bh1[j];
    b2p[jp] = bi2[j] + bh2[j];
}

__global__ __launch_bounds__(256) void gather_x0_split(
    const int* __restrict__ tokens, const float* __restrict__ emb,
    short* __restrict__ hi, short* __restrict__ lo) {
    int idx = blockIdx.x * 256 + threadIdx.x;    // 2048 blocks
    int p = idx >> 8;
    int k0 = (idx & 255) * 4;
    int tok = tokens[p];
    float4 v = *(const float4*)(emb + (size_t)tok * 1024 + k0);
    float a[4] = {v.x, v.y, v.z, v.w};
    short4v h, l;
    #pragma unroll
    for (int e = 0; e < 4; e++) {
        short q = f2bf(a[e]);
        h[e] = q;
        l[e] = f2bf(a[e] - bf2f(q));
    }
    *(short4v*)(hi + (size_t)p * 1024 + k0) = h;
    *(short4v*)(lo + (size_t)p * 1024 + k0) = l;
}

// ---------------- big GEMM (unchanged) ----------------
__global__ __launch_bounds__(256) void big_gemm(
    const short* __restrict__ A0, const short* __restrict__ A1s,
    const short* __restrict__ A2s, const short* __restrict__ A3s,
    const short* __restrict__ B0, const short* __restrict__ B1s,
    const short* __restrict__ B2s, const short* __restrict__ B3s,
    const float* __restrict__ bias, float* __restrict__ C, int K) {
    __shared__ short As[128 * 40];
    __shared__ short Bs[128 * 40];
    int tid = threadIdx.x;
    int n0 = blockIdx.x * 128;
    int m0 = blockIdx.y * 128;
    int lane = tid & 63, w = tid >> 6;
    int wm = (w >> 1) * 64, wn = (w & 1) * 64;
    int quad = lane >> 4, l16 = lane & 15;
    int srow = tid >> 2;
    int skc = (tid & 3) * 8;

    f32x4 acc[4][4];
    f32x4 z4 = {0.f, 0.f, 0.f, 0.f};
    #pragma unroll
    for (int i = 0; i < 4; i++)
        #pragma unroll
        for (int j = 0; j < 4; j++) acc[i][j] = z4;

    for (int k0 = 0; k0 < K; k0 += 32) {
        int seg = k0 >> 10;
        const short* Ab = (seg == 0) ? A0 : (seg == 1) ? A1s : (seg == 2) ? A2s : A3s;
        const short* Bb = (seg == 0) ? B0 : (seg == 1) ? B1s : (seg == 2) ? B2s : B3s;
        int kk = (k0 & 1023) + skc;
        const short* ga = Ab + (size_t)(m0 + srow) * 1024 + kk;
        const short* gb = Bb + (size_t)(n0 + srow) * 1024 + kk;
        bf16x8 av0 = *(const bf16x8*)ga;
        bf16x8 av1 = *(const bf16x8*)(ga + 64 * 1024);
        bf16x8 bv0 = *(const bf16x8*)gb;
        bf16x8 bv1 = *(const bf16x8*)(gb + 64 * 1024);
        __syncthreads();
        *(bf16x8*)&As[srow * 40 + skc] = av0;
        *(bf16x8*)&As[(srow + 64) * 40 + skc] = av1;
        *(bf16x8*)&Bs[srow * 40 + skc] = bv0;
        *(bf16x8*)&Bs[(srow + 64) * 40 + skc] = bv1;
        __syncthreads();
        bf16x8 af[4], bfr[4];
        #pragma unroll
        for (int im = 0; im < 4; im++)
            af[im] = *(const bf16x8*)&As[(wm + im * 16 + l16) * 40 + quad * 8];
        #pragma unroll
        for (int in = 0; in < 4; in++)
            bfr[in] = *(const bf16x8*)&Bs[(wn + in * 16 + l16) * 40 + quad * 8];
        #pragma unroll
        for (int im = 0; im < 4; im++)
            #pragma unroll
            for (int in = 0; in < 4; in++)
                acc[im][in] = __builtin_amdgcn_mfma_f32_16x16x32_bf16(
                    af[im], bfr[in], acc[im][in], 0, 0, 0);
    }
    #pragma unroll
    for (int in = 0; in < 4; in++) {
        int j = n0 + wn + in * 16 + l16;
        float bsv = bias[j];
        #pragma unroll
        for (int im = 0; im < 4; im++) {
            #pragma unroll
            for (int r = 0; r < 4; r++) {
                int p = m0 + wm + im * 16 + quad * 4 + r;
                C[(size_t)p * 4096 + j] = acc[im][in][r] + bsv;
            }
        }
    }
}

// ---------------- fused layer-1 recurrence (persistent) ----------
// 256 blocks x 256 thr. Block g owns gate-rows [g*16,g*16+16) of whh1.
// W-hi in LDS; W-lo from global (L2-resident). Cell state register-resident.
// h written via sc1 agent stores into TIME-INDEXED slots; t=0 skips h@W MFMA.
// Per-step tail: h sc1 stores -> syncthreads (vmcnt drain) -> arrival store ->
// H1f store + X12[t+1] prefetch (in flight) -> hierarchical wait.
__global__ __launch_bounds__(256, 1) void lstm1_fused(
    const short* __restrict__ Whi, const short* __restrict__ Wlo,
    const float* __restrict__ X12,
    short* __restrict__ H1hi, short* __restrict__ H1lo,
    float* __restrict__ H1f,
    unsigned* __restrict__ arrive, unsigned* __restrict__ release) {
    __shared__ short wsh[16 * 1032];
    __shared__ float red[4 * 64 * 16];

    int tid = threadIdx.x;
    int lane = tid & 63, w = tid >> 6;
    int quad = lane >> 4, l16 = lane & 15;
    int g = blockIdx.x;
    int kbase = w * 256;

    // stage hi-weight slice into LDS once
    for (int i = tid; i < 2048; i += 256) {
        int r = i >> 7;
        int k = (i & 127) * 8;
        *(bf16x8*)&wsh[r * 1032 + k] =
            *(const bf16x8*)(Whi + (size_t)(g * 16 + r) * 1024 + k);
    }

    int s = tid >> 2, dl = tid & 3;
    int d = g * 4 + dl;
    float creg = 0.f;           // register-resident cell state

    __syncthreads();

    const short* bhp = &wsh[l16 * 1032 + kbase + quad * 8];
    const short* blp = Wlo + (size_t)(g * 16 + l16) * 1024 + kbase + quad * 8;
    const float* xgp = X12 + (size_t)s * 4096 + g * 16 + dl * 4;

    float4 xg = *(const float4*)xgp;   // step-0 gate-bias slice

    for (int t = 0; t < 32; t++) {
        f32x4 acc[4];
        f32x4 z4 = {0.f, 0.f, 0.f, 0.f};
        acc[0] = z4; acc[1] = z4; acc[2] = z4; acc[3] = z4;

        if (t > 0) {   // h1[0] == 0 -> skip MFMA at t=0
            const short* ah = H1hi + (size_t)t * 65536 + (size_t)l16 * 1024 + kbase + quad * 8;
            const short* al = H1lo + (size_t)t * 65536 + (size_t)l16 * 1024 + kbase + quad * 8;
            #pragma unroll
            for (int i = 0; i < 8; i++) {
                int k = i * 32;
                bf16x8 Bh = *(const bf16x8*)(bhp + k);
                bf16x8 Bl = *(const bf16x8*)(blp + k);
                #pragma unroll
                for (int mt = 0; mt < 4; mt++) {
                    bf16x8 Ah = *(const bf16x8*)(ah + mt * 16 * 1024 + k);
                    bf16x8 Al = *(const bf16x8*)(al + mt * 16 * 1024 + k);
                    acc[mt] = __builtin_amdgcn_mfma_f32_16x16x32_bf16(Ah, Bh, acc[mt], 0, 0, 0);
                    acc[mt] = __builtin_amdgcn_mfma_f32_16x16x32_bf16(Al, Bh, acc[mt], 0, 0, 0);
                    acc[mt] = __builtin_amdgcn_mfma_f32_16x16x32_bf16(Ah, Bl, acc[mt], 0, 0, 0);
                }
            }
        }
        #pragma unroll
        for (int mt = 0; mt < 4; mt++)
            #pragma unroll
            for (int r = 0; r < 4; r++) {
                int sr = mt * 16 + quad * 4 + r;
                red[(w * 64 + sr) * 16 + l16] = acc[mt][r];
            }
        __syncthreads();

        float gi = 0.f, gf = 0.f, gg = 0.f, go = 0.f;
        #pragma unroll
        for (int w2 = 0; w2 < 4; w2++) {
            const float* rp = &red[(w2 * 64 + s) * 16 + dl * 4];
            gi += rp[0]; gf += rp[1]; gg += rp[2]; go += rp[3];
        }
        gi += xg.x; gf += xg.y; gg += xg.z; go += xg.w;
        float cn = sigm(gf) * creg + sigm(gi) * tanhf(gg);
        creg = cn;
        float hn = sigm(go) * tanhf(cn);
        short q = f2bf(hn);
        short ql = f2bf(hn - bf2f(q));
        // cross-block recurrence state: write-through (sc1) stores
        __hip_atomic_store(&H1hi[(size_t)(t + 1) * 65536 + s * 1024 + d], q,
                           __ATOMIC_RELAXED, __HIP_MEMORY_SCOPE_AGENT);
        __hip_atomic_store(&H1lo[(size_t)(t + 1) * 65536 + s * 1024 + d], ql,
                           __ATOMIC_RELAXED, __HIP_MEMORY_SCOPE_AGENT);
        __syncthreads();                       // drain: all waves' stores done
        if (t != 31) {
            unsigned tgt = (unsigned)(t + 1);
            if (tid == 0) sys_st(arrive + (size_t)g * 32, tgt);
            // off-chain work, in flight during the wait window:
            H1f[(size_t)t * 65536 + s * 1024 + d] = hn;   // consumed by attn later
            xg = *(const float4*)(xgp + (size_t)(t + 1) * 262144);
            if (g == 0) {
                // aggregator: 256 threads, one arrival slot each
                unsigned* my = arrive + (size_t)tid * 32;
                while (sys_ld(my) < tgt) __builtin_amdgcn_s_sleep(2);
                __syncthreads();
                if (tid == 0) sys_st(release, tgt);
            } else {
                if (tid == 0)
                    while (sys_ld(release) < tgt) __builtin_amdgcn_s_sleep(2);
                __syncthreads();
            }
            asm volatile("" ::: "memory");
        } else {
            H1f[(size_t)t * 65536 + s * 1024 + d] = hn;
        }
    }
}

// ---------------- fused layer-2 recurrence (persistent) ----------
// H2 is TIME-INDEXED (33 slots, lives in the dead H1F region); t=0 skips MFMA.
__global__ __launch_bounds__(256, 1) void lstm2_fused(
    const short* __restrict__ W, const float* __restrict__ X12,
    short* __restrict__ H2,
    float* __restrict__ out,
    unsigned* __restrict__ arrive, unsigned* __restrict__ release) {
    __shared__ short wsh[16 * 1032];
    __shared__ float red[4 * 64 * 16];

    int tid = threadIdx.x;
    int lane = tid & 63, w = tid >> 6;
    int quad = lane >> 4, l16 = lane & 15;
    int g = blockIdx.x;
    int kbase = w * 256;

    for (int i = tid; i < 2048; i += 256) {
        int r = i >> 7;
        int k = (i & 127) * 8;
        *(bf16x8*)&wsh[r * 1032 + k] =
            *(const bf16x8*)(W + (size_t)(g * 16 + r) * 1024 + k);
    }

    int s = tid >> 2, dl = tid & 3;
    int d = g * 4 + dl;
    float creg = 0.f;

    __syncthreads();

    const short* bp = &wsh[l16 * 1032 + kbase + quad * 8];
    const float* xgp = X12 + (size_t)s * 4096 + g * 16 + dl * 4;

    float4 xg = *(const float4*)xgp;

    for (int t = 0; t < 32; t++) {
        f32x4 acc[4];
        f32x4 z4 = {0.f, 0.f, 0.f, 0.f};
        acc[0] = z4; acc[1] = z4; acc[2] = z4; acc[3] = z4;

        if (t > 0) {   // h2[0] == 0 -> skip MFMA at t=0
            const short* ar = H2 + (size_t)t * 65536 + (size_t)l16 * 1024 + kbase + quad * 8;
            #pragma unroll
            for (int i = 0; i < 8; i++) {
                int k = i * 32;
                bf16x8 b = *(const bf16x8*)(bp + k);
                #pragma unroll
                for (int mt = 0; mt < 4; mt++) {
                    bf16x8 a = *(const bf16x8*)(ar + mt * 16 * 1024 + k);
                    acc[mt] = __builtin_amdgcn_mfma_f32_16x16x32_bf16(a, b, acc[mt], 0, 0, 0);
                }
            }
        }
        #pragma unroll
        for (int mt = 0; mt < 4; mt++)
            #pragma unroll
            for (int r = 0; r < 4; r++) {
                int sr = mt * 16 + quad * 4 + r;
                red[(w * 64 + sr) * 16 + l16] = acc[mt][r];
            }
        __syncthreads();

        float gi = 0.f, gf = 0.f, gg = 0.f, go = 0.f;
        #pragma unroll
        for (int w2 = 0; w2 < 4; w2++) {
            const float* rp = &red[(w2 * 64 + s) * 16 + dl * 4];
            gi += rp[0]; gf += rp[1]; gg += rp[2]; go += rp[3];
        }
        gi += xg.x; gf += xg.y; gg += xg.z; go += xg.w;
        float cn = sigm(gf) * creg + sigm(gi) * tanhf(gg);
        creg = cn;
        float hn = sigm(go) * tanhf(cn);
        __hip_atomic_store(&H2[(size_t)(t + 1) * 65536 + s * 1024 + d], f2bf(hn),
                           __ATOMIC_RELAXED, __HIP_MEMORY_SCOPE_AGENT);
        __syncthreads();                       // drain
        if (t != 31) {
            unsigned tgt = (unsigned)(t + 1);
            if (tid == 0) sys_st(arrive + (size_t)g * 32, tgt);
            out[(size_t)t * 65536 + s * 1024 + d] = hn;   // host-visible later
            xg = *(const float4*)(xgp + (size_t)(t + 1) * 262144);
            if (g == 0) {
                unsigned* my = arrive + (size_t)tid * 32;
                while (sys_ld(my) < tgt) __builtin_amdgcn_s_sleep(2);
                __syncthreads();
                if (tid == 0) sys_st(release, tgt);
            } else {
                if (tid == 0)
                    while (sys_ld(release) < tgt) __builtin_amdgcn_s_sleep(2);
                __syncthreads();
            }
            asm volatile("" ::: "memory");
        } else {
            out[(size_t)t * 65536 + s * 1024 + d] = hn;
        }
    }
}

// ---------------- batched attention (fp32, unchanged) ----------------
__global__ __launch_bounds__(256) void attn_batch(
    const float* __restrict__ H1f, const float* __restrict__ F,
    short* __restrict__ Vhi, short* __restrict__ Vlo) {
    __shared__ float vs[4][4][1024];
    int n = blockIdx.x, tg = blockIdx.y;
    int tid = threadIdx.x, lane = tid & 63, w = tid >> 6;

    float h[4][16];
    #pragma unroll
    for (int tt = 0; tt < 4; tt++) {
        const float* hp = H1f + ((size_t)((tg * 4 + tt) * 64 + n)) * 1024 + lane * 16;
        #pragma unroll
        for (int j = 0; j < 4; j++) {
            float4 v = *(const float4*)(hp + j * 4);
            h[tt][j * 4 + 0] = v.x; h[tt][j * 4 + 1] = v.y;
            h[tt][j * 4 + 2] = v.z; h[tt][j * 4 + 3] = v.w;
        }
    }
    float vacc[4][16];
    #pragma unroll
    for (int tt = 0; tt < 4; tt++)
        #pragma unroll
        for (int j = 0; j < 16; j++) vacc[tt][j] = 0.f;

    const float* Fn = F + ((size_t)n * 196) * 1024 + lane * 16;
    for (int l = w; l < 196; l += 4) {
        const float* fr = Fn + (size_t)l * 1024;
        float f[16];
        #pragma unroll
        for (int j = 0; j < 4; j++) {
            float4 v = *(const float4*)(fr + j * 4);
            f[j * 4 + 0] = v.x; f[j * 4 + 1] = v.y;
            f[j * 4 + 2] = v.z; f[j * 4 + 3] = v.w;
        }
        float p[4] = {0.f, 0.f, 0.f, 0.f};
        #pragma unroll
        for (int tt = 0; tt < 4; tt++)
            #pragma unroll
            for (int j = 0; j < 16; j++) p[tt] += f[j] * h[tt][j];
        #pragma unroll
        for (int off = 32; off > 0; off >>= 1) {
            #pragma unroll
            for (int tt = 0; tt < 4; tt++) p[tt] += __shfl_xor(p[tt], off, 64);
        }
        #pragma unroll
        for (int tt = 0; tt < 4; tt++)
            #pragma unroll
            for (int j = 0; j < 16; j++) vacc[tt][j] += p[tt] * f[j];
    }
    #pragma unroll
    for (int tt = 0; tt < 4; tt++)
        #pragma unroll
        for (int j4 = 0; j4 < 4; j4++) {
            float4 v;
            v.x = vacc[tt][j4 * 4 + 0]; v.y = vacc[tt][j4 * 4 + 1];
            v.z = vacc[tt][j4 * 4 + 2]; v.w = vacc[tt][j4 * 4 + 3];
            *(float4*)&vs[w][tt][lane * 16 + j4 * 4] = v;
        }
    __syncthreads();
    int d0 = tid * 4;
    #pragma unroll
    for (int tt = 0; tt < 4; tt++) {
        float4 a = *(const float4*)&vs[0][tt][d0];
        float4 b = *(const float4*)&vs[1][tt][d0];
        float4 cc = *(const float4*)&vs[2][tt][d0];
        float4 e = *(const float4*)&vs[3][tt][d0];
        float sv[4];
        sv[0] = a.x + b.x + cc.x + e.x;
        sv[1] = a.y + b.y + cc.y + e.y;
        sv[2] = a.z + b.z + cc.z + e.z;
        sv[3] = a.w + b.w + cc.w + e.w;
        short4v b1, b2;
        #pragma unroll
        for (int e2 = 0; e2 < 4; e2++) {
            short q = f2bf(sv[e2]);
            b1[e2] = q;
            b2[e2] = f2bf(sv[e2] - bf2f(q));
        }
        size_t row = ((size_t)(tg * 4 + tt) * 64 + n) * 1024 + d0;
        *(short4v*)(Vhi + row) = b1;
        *(short4v*)(Vlo + row) = b2;
    }
}

// ---------------- host launch ----------------
extern "C" void kernel_launch(void* const* d_in, const int* in_sizes, int n_in,
                              void* d_out, int out_size, void* d_ws, size_t ws_size,
                              hipStream_t stream) {
    const int*   tokens = (const int*)d_in[0];
    const float* imgf   = (const float*)d_in[1];
    const float* emb    = (const float*)d_in[2];
    const float* w_ih1  = (const float*)d_in[3];
    const float* w_hh1  = (const float*)d_in[4];
    const float* b_ih1  = (const float*)d_in[5];
    const float* b_hh1  = (const float*)d_in[6];
    const float* w_ih2  = (const float*)d_in[7];
    const float* w_hh2  = (const float*)d_in[8];
    const float* b_ih2  = (const float*)d_in[9];
    const float* b_hh2  = (const float*)d_in[10];
    float* out = (float*)d_out;
    char* ws = (char*)d_ws;

    unsigned* arrive1  = (unsigned*)(ws + OFF_C1);            // 256 x 128B
    unsigned* release1 = (unsigned*)(ws + OFF_C1 + 32768u);   // own line
    unsigned* arrive2  = (unsigned*)(ws + OFF_C1 + 65536u);   // 256 x 128B
    unsigned* release2 = (unsigned*)(ws + OFF_C1 + 98304u);   // own line
    short* H1hi   = (short*)(ws + OFF_H1HI);
    short* H1lo   = (short*)(ws + OFF_H1LO);
    float* H1f    = (float*)(ws + OFF_H1F);
    short* H2     = (short*)(ws + OFF_H1F);    // time-indexed h2 slots (after attn)
    short* X0hi   = (short*)(ws + OFF_X0HI);
    short* X0lo   = (short*)(ws + OFF_X0LO);
    short* Vhi    = (short*)(ws + OFF_X0HI);   // alias (X0 dead after X1 GEMM)
    short* Vlo    = (short*)(ws + OFF_X0LO);
    float* bias1p = (float*)(ws + OFF_B1);
    float* bias2p = (float*)(ws + OFF_B2);
    short* whh1hi = (short*)(ws + OFF_WHH1HI);
    short* whh1lo = (short*)(ws + OFF_WHH1LO);
    short* wih1hi = (short*)(ws + OFF_WIH1HI);
    short* wih1lo = (short*)(ws + OFF_WIH1LO);
    short* whh2hi = (short*)(ws + OFF_WHH2HI);
    short* wvhi   = (short*)(ws + OFF_WVHI);
    short* wvlo   = (short*)(ws + OFF_WVLO);
    short* wh2hi  = (short*)(ws + OFF_WH2HI);
    float* X12    = (float*)(ws + OFF_X12);
    short* dump   = (short*)(ws + OFF_X12);    // prep-time scratch, overwritten later

    // prep (cell state register-resident; t=0 skips h@W -> no h-slot zeroing;
    // barrier region zeroed with SYSTEM-scope stores so polls observe it)
    zero_slots<<<128, 256, 0, stream>>>((unsigned*)(ws + OFF_C1));  // 128KB
    perm_w_split<<<4096, 256, 0, stream>>>(w_hh1, whh1hi, whh1lo, 1024, 0);
    perm_w_split<<<4096, 256, 0, stream>>>(w_ih1, wih1hi, wih1lo, 1024, 0);
    perm_w_split<<<4096, 256, 0, stream>>>(w_hh2, whh2hi, dump, 1024, 0);
    perm_w_split<<<4096, 256, 0, stream>>>(w_ih2, wvhi, wvlo, 2048, 0);
    perm_w_split<<<4096, 256, 0, stream>>>(w_ih2, wh2hi, dump, 2048, 1024);
    bias_prep<<<16, 256, 0, stream>>>(b_ih1, b_hh1, b_ih2, b_hh2, bias1p, bias2p);
    gather_x0_split<<<2048, 256, 0, stream>>>(tokens, emb, X0hi, X0lo);

    // X1 = (X0hi+X0lo) @ (wih1hi+wih1lo)^T + bias1, triple-split, K=3072
    big_gemm<<<dim3(32, 16), 256, 0, stream>>>(
        X0hi, X0lo, X0hi, X0hi,
        wih1hi, wih1hi, wih1lo, wih1hi,
        bias1p, X12, 3072);

    // fused layer-1 recurrence (one normal launch, 32 steps inside)
    lstm1_fused<<<256, 256, 0, stream>>>(
        whh1hi, whh1lo, X12, H1hi, H1lo, H1f, arrive1, release1);

    // batched attention (fp32 in, compensated double-bf16 out)
    attn_batch<<<dim3(64, 8), 256, 0, stream>>>(H1f, imgf, Vhi, Vlo);

    // X2 = v@wv (triple-split) + h1@wh + bias2, K=4096
    big_gemm<<<dim3(32, 16), 256, 0, stream>>>(
        Vhi, Vlo, Vhi, H1hi + 65536,
        wvhi, wvhi, wvlo, wh2hi,
        bias2p, X12, 4096);

    // fused layer-2 recurrence (one normal launch, 32 steps inside)
    lstm2_fused<<<256, 256, 0, stream>>>(
        whh2hi, X12, H2, out, arrive2, release2);
}